// Round 3
// baseline (9578.088 us; speedup 1.0000x reference)
//
#include <hip/hip_runtime.h>
#include <stdint.h>
#include <string.h>

// Problem constants
#define NB   131072   // batch
#define DIN  128
#define HD   256      // hidden
#define VT   6        // total vocab
#define TS   6        // steps
// Tiling: BM=128 rows/block, 512 threads, per-thread 8 rows x 8 cols
#define BM   128
#define NTH  512
#define KB   8        // k-tile rows

struct Keys { uint32_t a[6]; uint32_t b[6]; };

// ---- JAX threefry2x32 (20 rounds), bit-exact ----
__host__ __device__ inline void tf2x32(uint32_t k0, uint32_t k1,
                                       uint32_t c0, uint32_t c1,
                                       uint32_t& o0, uint32_t& o1) {
  uint32_t ks2 = k0 ^ k1 ^ 0x1BD11BDAu;
  uint32_t x0 = c0 + k0, x1 = c1 + k1;
#define TFR(d) { x0 += x1; x1 = (x1 << (d)) | (x1 >> (32 - (d))); x1 ^= x0; }
  TFR(13) TFR(15) TFR(26) TFR(6)
  x0 += k1;  x1 += ks2 + 1u;
  TFR(17) TFR(29) TFR(16) TFR(24)
  x0 += ks2; x1 += k0 + 2u;
  TFR(13) TFR(15) TFR(26) TFR(6)
  x0 += k0;  x1 += k1 + 3u;
  TFR(17) TFR(29) TFR(16) TFR(24)
  x0 += k1;  x1 += ks2 + 4u;
  TFR(13) TFR(15) TFR(26) TFR(6)
  x0 += ks2; x1 += k0 + 5u;
#undef TFR
  o0 = x0; o1 = x1;
}

// ---- Kernel A: pre_g[c][j] = xin_c @ Wg_top[:,j]
// codes: 0..5 = W_embed[c]+b_embed, 6 = b_embed (stopped), 7 = start_embed
__global__ void pre_kernel(const float* __restrict__ W_embed,
                           const float* __restrict__ b_embed,
                           const float* __restrict__ start_embed,
                           const float* __restrict__ W_z,
                           const float* __restrict__ W_r,
                           const float* __restrict__ W_h,
                           float* __restrict__ pre /* [3][8][256] */) {
  __shared__ float xin[HD];
  const int c = blockIdx.x & 7;
  const int g = blockIdx.x >> 3;   // 0..2
  const int j = threadIdx.x;       // 0..255
  float v;
  if (c < 6)       v = W_embed[c * HD + j] + b_embed[j];
  else if (c == 6) v = b_embed[j];
  else             v = start_embed[j];
  xin[j] = v;
  __syncthreads();
  const float* Wg = (g == 0) ? W_z : (g == 1) ? W_r : W_h;  // top half rows 0..255
  float acc = 0.f;
  for (int k = 0; k < HD; ++k) acc += xin[k] * Wg[k * HD + j];
  pre[(g * 8 + c) * HD + j] = acc;
}

__device__ __forceinline__ float sigf(float v) { return 1.0f / (1.0f + expf(-v)); }

__device__ __forceinline__ void f4fma(float4& a, float s, float4 w) {
  a.x += s * w.x; a.y += s * w.y; a.z += s * w.z; a.w += s * w.w;
}

// GEMM over K tiles; A = h_lds (swizzled), W streamed global->LDS, reg prefetch.
// DUAL=1 runs two W streams (z and r) sharing the A reads.
template<int DUAL>
__device__ __forceinline__ void gemm_pass(const float4* __restrict__ W0f,
                                          const float4* __restrict__ W1f,
                                          int NT,
                                          const float4* __restrict__ h4,
                                          float4* __restrict__ wt0,
                                          float4* __restrict__ wt1,
                                          int tid, int rg, int cg,
                                          float4 acc0[8][2], float4 acc1[8][2]) {
  float4 p0 = W0f[tid];
  float4 p1;
  if (DUAL) p1 = W1f[tid];
  for (int kt = 0; kt < NT; ++kt) {
    __syncthreads();                 // all readers of previous tile done
    wt0[tid] = p0;
    if (DUAL) wt1[tid] = p1;
    __syncthreads();                 // tile visible
    if (kt + 1 < NT) {
      p0 = W0f[(kt + 1) * 512 + tid];
      if (DUAL) p1 = W1f[(kt + 1) * 512 + tid];
    }
#pragma unroll
    for (int j = 0; j < 2; ++j) {
      const int ac4 = (2 * kt + j) ^ rg;        // swizzled k-chunk column
      float4 a[8];
#pragma unroll
      for (int r = 0; r < 8; ++r) a[r] = h4[(rg * 8 + r) * 64 + ac4];
#pragma unroll
      for (int kk = 0; kk < 4; ++kk) {
        const int wrow = j * 4 + kk;
        float4 w00 = wt0[wrow * 64 + cg];
        float4 w01 = wt0[wrow * 64 + 32 + cg];
        float4 w10, w11;
        if (DUAL) { w10 = wt1[wrow * 64 + cg]; w11 = wt1[wrow * 64 + 32 + cg]; }
#pragma unroll
        for (int r = 0; r < 8; ++r) {
          const float av = (kk == 0) ? a[r].x : (kk == 1) ? a[r].y
                         : (kk == 2) ? a[r].z : a[r].w;
          f4fma(acc0[r][0], av, w00);
          f4fma(acc0[r][1], av, w01);
          if (DUAL) { f4fma(acc1[r][0], av, w10); f4fma(acc1[r][1], av, w11); }
        }
      }
    }
  }
}

// ---- main kernel: persistent per-row-block rollout
__launch_bounds__(NTH, 2)
__global__ void main_kernel(const float* __restrict__ x,
                            const float* __restrict__ W_enc,
                            const float* __restrict__ b_enc,
                            const float* __restrict__ W_z, const float* __restrict__ b_z,
                            const float* __restrict__ W_r, const float* __restrict__ b_r,
                            const float* __restrict__ W_h, const float* __restrict__ b_h,
                            const float* __restrict__ W_out, const float* __restrict__ b_out,
                            const float* __restrict__ pre,
                            float* __restrict__ out, Keys keys) {
  __shared__ __align__(16) float h_lds[BM * HD];     // 131072 B (XOR-swizzled)
  __shared__ __align__(16) float wt0_l[KB * HD];     //   8192 B
  __shared__ __align__(16) float wt1_l[KB * HD];     //   8192 B
  __shared__ __align__(16) float wout_t[VT * HD];    //   6144 B  [v][k]
  __shared__ unsigned state[BM];                     // code|stopped<<3|len<<4
  __shared__ float tlp[BM];

  float4* h4  = (float4*)h_lds;
  float4* wt0 = (float4*)wt0_l;
  float4* wt1 = (float4*)wt1_l;
  const float4* pre4 = (const float4*)pre;

  const int tid = threadIdx.x;
  const int rg  = tid >> 5;          // 0..15 (row group of 8)
  const int cg  = tid & 31;          // 0..31 (col group: cols {4cg..+3, 128+4cg..+3})
  const int b0  = blockIdx.x * BM;

  // stage W_out transposed; init per-row state
  for (int idx = tid; idx < HD * VT; idx += NTH) {
    int k = idx & 255, v = idx >> 8;
    wout_t[v * HD + k] = W_out[k * VT + v];
  }
  if (tid < BM) { state[tid] = 7u; tlp[tid] = 0.f; }

  // stage x tile into h_lds cols c4a 0..31 (swizzled)
  const float4* x4 = (const float4*)x;
#pragma unroll
  for (int s = 0; s < 8; ++s) {
    int f = s * NTH + tid;                  // 4096 float4s
    int row = f >> 5, c4a = f & 31;
    h4[row * 64 + (c4a ^ (row >> 3))] = x4[(size_t)(b0 + row) * 32 + c4a];
  }

  float4 acc0[8][2], acc1[8][2], zz[8][2], hold[8][2];

  // ---- encoder: h0 = x @ W_enc + b_enc ----
#pragma unroll
  for (int r = 0; r < 8; ++r) {
    acc0[r][0] = make_float4(0.f, 0.f, 0.f, 0.f);
    acc0[r][1] = make_float4(0.f, 0.f, 0.f, 0.f);
  }
  gemm_pass<0>((const float4*)W_enc, nullptr, DIN / KB, h4, wt0, wt1,
               tid, rg, cg, acc0, acc1);
  __syncthreads();  // all a-reads of x done before overwriting with h
  {
    const float4* be4 = (const float4*)b_enc;
    float4 bb0 = be4[cg], bb1 = be4[32 + cg];
#pragma unroll
    for (int r = 0; r < 8; ++r) {
      int row = rg * 8 + r;
      float4 o0 = acc0[r][0], o1 = acc0[r][1];
      o0.x += bb0.x; o0.y += bb0.y; o0.z += bb0.z; o0.w += bb0.w;
      o1.x += bb1.x; o1.y += bb1.y; o1.z += bb1.z; o1.w += bb1.w;
      h4[row * 64 + (cg ^ rg)]        = o0;
      h4[row * 64 + ((32 + cg) ^ rg)] = o1;
    }
  }
  // (next gemm_pass's first barrier publishes h)

  for (int t = 0; t < TS; ++t) {
    // ---- fused z+r gemms (A = h) ----
#pragma unroll
    for (int r = 0; r < 8; ++r) {
      unsigned code = state[rg * 8 + r] & 7u;
      acc0[r][0] = pre4[(0 * 8 + code) * 64 + cg];
      acc0[r][1] = pre4[(0 * 8 + code) * 64 + 32 + cg];
      acc1[r][0] = pre4[(1 * 8 + code) * 64 + cg];
      acc1[r][1] = pre4[(1 * 8 + code) * 64 + 32 + cg];
    }
    gemm_pass<1>((const float4*)(W_z + 256 * HD), (const float4*)(W_r + 256 * HD),
                 HD / KB, h4, wt0, wt1, tid, rg, cg, acc0, acc1);
    __syncthreads();  // all a-reads of h done
    {
      const float4* bz4 = (const float4*)b_z;
      const float4* br4 = (const float4*)b_r;
      float4 bz0 = bz4[cg], bz1 = bz4[32 + cg];
      float4 br0 = br4[cg], br1 = br4[32 + cg];
#pragma unroll
      for (int r = 0; r < 8; ++r) {
        int row = rg * 8 + r;
        float4 hv0 = h4[row * 64 + (cg ^ rg)];
        float4 hv1 = h4[row * 64 + ((32 + cg) ^ rg)];
        hold[r][0] = hv0; hold[r][1] = hv1;
        float4 z0, z1, r0, r1;
        z0.x = sigf(acc0[r][0].x + bz0.x); z0.y = sigf(acc0[r][0].y + bz0.y);
        z0.z = sigf(acc0[r][0].z + bz0.z); z0.w = sigf(acc0[r][0].w + bz0.w);
        z1.x = sigf(acc0[r][1].x + bz1.x); z1.y = sigf(acc0[r][1].y + bz1.y);
        z1.z = sigf(acc0[r][1].z + bz1.z); z1.w = sigf(acc0[r][1].w + bz1.w);
        r0.x = sigf(acc1[r][0].x + br0.x); r0.y = sigf(acc1[r][0].y + br0.y);
        r0.z = sigf(acc1[r][0].z + br0.z); r0.w = sigf(acc1[r][0].w + br0.w);
        r1.x = sigf(acc1[r][1].x + br1.x); r1.y = sigf(acc1[r][1].y + br1.y);
        r1.z = sigf(acc1[r][1].z + br1.z); r1.w = sigf(acc1[r][1].w + br1.w);
        zz[r][0] = z0; zz[r][1] = z1;
        float4 rh0, rh1;
        rh0.x = r0.x * hv0.x; rh0.y = r0.y * hv0.y; rh0.z = r0.z * hv0.z; rh0.w = r0.w * hv0.w;
        rh1.x = r1.x * hv1.x; rh1.y = r1.y * hv1.y; rh1.z = r1.z * hv1.z; rh1.w = r1.w * hv1.w;
        h4[row * 64 + (cg ^ rg)]        = rh0;
        h4[row * 64 + ((32 + cg) ^ rg)] = rh1;
      }
    }
    __syncthreads();  // rh published

    // ---- candidate gate (A = r*h) ----
#pragma unroll
    for (int r = 0; r < 8; ++r) {
      unsigned code = state[rg * 8 + r] & 7u;
      acc0[r][0] = pre4[(2 * 8 + code) * 64 + cg];
      acc0[r][1] = pre4[(2 * 8 + code) * 64 + 32 + cg];
    }
    gemm_pass<0>((const float4*)(W_h + 256 * HD), nullptr, HD / KB,
                 h4, wt0, wt1, tid, rg, cg, acc0, acc1);
    __syncthreads();  // all a-reads of rh done
    {
      const float4* bh4 = (const float4*)b_h;
      float4 bh0 = bh4[cg], bh1 = bh4[32 + cg];
#pragma unroll
      for (int r = 0; r < 8; ++r) {
        int row = rg * 8 + r;
        float4 ht0, ht1;
        ht0.x = tanhf(acc0[r][0].x + bh0.x); ht0.y = tanhf(acc0[r][0].y + bh0.y);
        ht0.z = tanhf(acc0[r][0].z + bh0.z); ht0.w = tanhf(acc0[r][0].w + bh0.w);
        ht1.x = tanhf(acc0[r][1].x + bh1.x); ht1.y = tanhf(acc0[r][1].y + bh1.y);
        ht1.z = tanhf(acc0[r][1].z + bh1.z); ht1.w = tanhf(acc0[r][1].w + bh1.w);
        float4 z0 = zz[r][0], z1 = zz[r][1];
        float4 ho0 = hold[r][0], ho1 = hold[r][1], hn0, hn1;
        hn0.x = (1.0f - z0.x) * ho0.x + z0.x * ht0.x;
        hn0.y = (1.0f - z0.y) * ho0.y + z0.y * ht0.y;
        hn0.z = (1.0f - z0.z) * ho0.z + z0.z * ht0.z;
        hn0.w = (1.0f - z0.w) * ho0.w + z0.w * ht0.w;
        hn1.x = (1.0f - z1.x) * ho1.x + z1.x * ht1.x;
        hn1.y = (1.0f - z1.y) * ho1.y + z1.y * ht1.y;
        hn1.z = (1.0f - z1.z) * ho1.z + z1.z * ht1.z;
        hn1.w = (1.0f - z1.w) * ho1.w + z1.w * ht1.w;
        h4[row * 64 + (cg ^ rg)]        = hn0;
        h4[row * 64 + ((32 + cg) ^ rg)] = hn1;
      }
    }
    __syncthreads();  // h_new visible for logits

    // ---- logits + sampling: 4 lanes per row ----
    {
      const int m = tid >> 2, q = tid & 3, mrg = m >> 3;
      float l[VT] = {0.f, 0.f, 0.f, 0.f, 0.f, 0.f};
#pragma unroll
      for (int jj = 0; jj < 16; ++jj) {
        int j = (jj + ((m & 7) << 1)) & 15;     // bank-decorrelating rotation
        int c4a = q * 16 + j;
        float4 hv = h4[m * 64 + (c4a ^ mrg)];
        const float4* wt4 = (const float4*)wout_t;
#pragma unroll
        for (int v = 0; v < VT; ++v) {
          float4 w = wt4[v * 64 + c4a];
          l[v] += hv.x * w.x + hv.y * w.y + hv.z * w.z + hv.w * w.w;
        }
      }
#pragma unroll
      for (int v = 0; v < VT; ++v) {
        l[v] += __shfl_xor(l[v], 1, 64);
        l[v] += __shfl_xor(l[v], 2, 64);
      }
      if (q == 0) {
        const int row = b0 + m;
        unsigned st = state[m];
        if (!(st & 8u)) {
#pragma unroll
          for (int v = 0; v < VT; ++v) l[v] += b_out[v];
          // gumbel-argmax, bit-matching jax.random.categorical
          // (threefry_partitionable: counter (0, j), bits = o0 ^ o1)
          const uint32_t k0 = keys.a[t], k1 = keys.b[t];
          float best = 0.f; int tok = 0;
#pragma unroll
          for (int v = 0; v < VT; ++v) {
            uint32_t j = (uint32_t)row * 6u + (uint32_t)v;
            uint32_t o0, o1;
            tf2x32(k0, k1, 0u, j, o0, o1);
            uint32_t bits = o0 ^ o1;
            float f = __uint_as_float((bits >> 9) | 0x3f800000u) - 1.0f;
            float u = (f > 0.f) ? f : 1.175494350822288e-38f;
            float lg1 = (float)log((double)u);
            float lg2 = (float)log((double)(-lg1));
            float val = l[v] + (-lg2);
            if (v == 0 || val > best) { best = val; tok = v; }
          }
          float lmax = l[0];
#pragma unroll
          for (int v = 1; v < VT; ++v) lmax = fmaxf(lmax, l[v]);
          float s = 0.f;
#pragma unroll
          for (int v = 0; v < VT; ++v) s += expf(l[v] - lmax);
          float lp = (l[tok] - lmax) - logf(s);
          tlp[m] += lp;
          const bool is_stop = (tok == VT - 1);
          unsigned len = ((st >> 4) & 7u) + (is_stop ? 0u : 1u);
#pragma unroll
          for (int v = 0; v < VT; ++v)
            out[(size_t)row * (TS * VT) + t * VT + v] = (v == tok) ? 1.0f : 0.0f;
          state[m] = (unsigned)tok | (is_stop ? 8u : 0u) | (len << 4);
        } else {
#pragma unroll
          for (int v = 0; v < VT; ++v)
            out[(size_t)row * (TS * VT) + t * VT + v] = 0.0f;
          state[m] = 6u | 8u | (st & 0x70u);
        }
      }
    }
    __syncthreads();  // state/tlp visible for next step
  }

  if (tid < BM) {
    const int row = b0 + tid;
    out[(size_t)NB * (TS * VT) + row]      = tlp[tid];
    out[(size_t)NB * (TS * VT) + NB + row] = (float)((state[tid] >> 4) & 7u);
  }
}

extern "C" void kernel_launch(void* const* d_in, const int* in_sizes, int n_in,
                              void* d_out, int out_size, void* d_ws, size_t ws_size,
                              hipStream_t stream) {
  (void)in_sizes; (void)n_in; (void)out_size; (void)ws_size;
  const float* x          = (const float*)d_in[0];
  const float* W_enc      = (const float*)d_in[1];
  const float* b_enc      = (const float*)d_in[2];
  const float* W_embed    = (const float*)d_in[3];
  const float* b_embed    = (const float*)d_in[4];
  const float* W_z        = (const float*)d_in[5];
  const float* b_z        = (const float*)d_in[6];
  const float* W_r        = (const float*)d_in[7];
  const float* b_r        = (const float*)d_in[8];
  const float* W_h        = (const float*)d_in[9];
  const float* b_h        = (const float*)d_in[10];
  const float* W_out      = (const float*)d_in[11];
  const float* b_out      = (const float*)d_in[12];
  const float* start_embed= (const float*)d_in[13];
  float* out = (float*)d_out;
  float* pre = (float*)d_ws;   // 3*8*256 floats = 24 KiB

  pre_kernel<<<24, 256, 0, stream>>>(W_embed, b_embed, start_embed, W_z, W_r, W_h, pre);

  // keys = jax.random.split(jax.random.key(42), 6), partitionable mode
  Keys K;
  for (int t = 0; t < 6; ++t) {
    uint32_t o0, o1;
    tf2x32(0u, 42u, 0u, (uint32_t)t, o0, o1);
    K.a[t] = o0; K.b[t] = o1;
  }

  main_kernel<<<NB / BM, NTH, 0, stream>>>(x, W_enc, b_enc, W_z, b_z, W_r, b_r,
                                           W_h, b_h, W_out, b_out, pre, out, K);
}

// Round 4
// 5513.560 us; speedup vs baseline: 1.7372x; 1.7372x over previous
//
#include <hip/hip_runtime.h>
#include <stdint.h>
#include <string.h>

// Problem constants
#define NB   131072   // batch
#define DIN  128
#define HD   256      // hidden
#define VT   6        // total vocab
#define TS   6        // steps
// Tiling: BM=64 rows/block, 128 threads, per-thread 8 rows x 16 cols
#define BM   64
#define NTH  128

struct Keys { uint32_t a[6]; uint32_t b[6]; };

// ---- JAX threefry2x32 (20 rounds), bit-exact ----
__host__ __device__ inline void tf2x32(uint32_t k0, uint32_t k1,
                                       uint32_t c0, uint32_t c1,
                                       uint32_t& o0, uint32_t& o1) {
  uint32_t ks2 = k0 ^ k1 ^ 0x1BD11BDAu;
  uint32_t x0 = c0 + k0, x1 = c1 + k1;
#define TFR(d) { x0 += x1; x1 = (x1 << (d)) | (x1 >> (32 - (d))); x1 ^= x0; }
  TFR(13) TFR(15) TFR(26) TFR(6)
  x0 += k1;  x1 += ks2 + 1u;
  TFR(17) TFR(29) TFR(16) TFR(24)
  x0 += ks2; x1 += k0 + 2u;
  TFR(13) TFR(15) TFR(26) TFR(6)
  x0 += k0;  x1 += k1 + 3u;
  TFR(17) TFR(29) TFR(16) TFR(24)
  x0 += k1;  x1 += ks2 + 4u;
  TFR(13) TFR(15) TFR(26) TFR(6)
  x0 += ks2; x1 += k0 + 5u;
#undef TFR
  o0 = x0; o1 = x1;
}

// ---- Kernel A: pre_g[c][j] = xin_c @ Wg_top[:,j]
// codes: 0..5 = W_embed[c]+b_embed, 6 = b_embed (stopped), 7 = start_embed
__global__ void pre_kernel(const float* __restrict__ W_embed,
                           const float* __restrict__ b_embed,
                           const float* __restrict__ start_embed,
                           const float* __restrict__ W_z,
                           const float* __restrict__ W_r,
                           const float* __restrict__ W_h,
                           float* __restrict__ pre /* [3][8][256] */) {
  __shared__ float xin[HD];
  const int c = blockIdx.x & 7;
  const int g = blockIdx.x >> 3;   // 0..2
  const int j = threadIdx.x;       // 0..255
  float v;
  if (c < 6)       v = W_embed[c * HD + j] + b_embed[j];
  else if (c == 6) v = b_embed[j];
  else             v = start_embed[j];
  xin[j] = v;
  __syncthreads();
  const float* Wg = (g == 0) ? W_z : (g == 1) ? W_r : W_h;  // top half rows 0..255
  float acc = 0.f;
  for (int k = 0; k < HD; ++k) acc += xin[k] * Wg[k * HD + j];
  pre[(g * 8 + c) * HD + j] = acc;
}

__device__ __forceinline__ float sigf(float v) { return 1.0f / (1.0f + expf(-v)); }

__device__ __forceinline__ void f4fma(float4& a, float s, float4 w) {
  a.x += s * w.x; a.y += s * w.y; a.z += s * w.z; a.w += s * w.w;
}

// GEMM over K (A = h4 swizzled in LDS, W streamed global->LDS w/ register prefetch)
// Thread tile: 8 rows (rg*8+r) x 16 cols (chunks cg+16j, j=0..3).
__device__ __forceinline__ void gemm(const float4* __restrict__ W4, int NT,
                                     const float4* __restrict__ h4,
                                     float4* __restrict__ wt4,
                                     int tid, int rg, int cg,
                                     float4 acc[8][4]) {
  float4 p0 = W4[tid], p1 = W4[128 + tid], p2 = W4[256 + tid], p3 = W4[384 + tid];
  for (int kt = 0; kt < NT; ++kt) {
    __syncthreads();                     // readers of previous tile done
    wt4[tid] = p0; wt4[128 + tid] = p1; wt4[256 + tid] = p2; wt4[384 + tid] = p3;
    __syncthreads();                     // tile visible
    if (kt + 1 < NT) {
      const float4* n = W4 + (size_t)(kt + 1) * 512;
      p0 = n[tid]; p1 = n[128 + tid]; p2 = n[256 + tid]; p3 = n[384 + tid];
    }
#pragma unroll
    for (int j = 0; j < 2; ++j) {
      const int ac4 = (2 * kt + j) ^ rg;          // swizzled k-chunk
      float4 a[8];
#pragma unroll
      for (int r = 0; r < 8; ++r) a[r] = h4[(rg * 8 + r) * 64 + ac4];
#pragma unroll
      for (int kk = 0; kk < 4; ++kk) {
        const int wrow = j * 4 + kk;
        float4 w0 = wt4[wrow * 64 + cg];
        float4 w1 = wt4[wrow * 64 + 16 + cg];
        float4 w2 = wt4[wrow * 64 + 32 + cg];
        float4 w3 = wt4[wrow * 64 + 48 + cg];
#pragma unroll
        for (int r = 0; r < 8; ++r) {
          const float av = (kk == 0) ? a[r].x : (kk == 1) ? a[r].y
                         : (kk == 2) ? a[r].z : a[r].w;
          f4fma(acc[r][0], av, w0);
          f4fma(acc[r][1], av, w1);
          f4fma(acc[r][2], av, w2);
          f4fma(acc[r][3], av, w3);
        }
      }
    }
  }
}

// ---- main kernel: persistent per-row-block rollout
__launch_bounds__(NTH, 1)   // min 1 wave/EU -> VGPR budget 512 (parked z/hold -> AGPRs)
__global__ void main_kernel(const float* __restrict__ x,
                            const float* __restrict__ W_enc,
                            const float* __restrict__ b_enc,
                            const float* __restrict__ W_z, const float* __restrict__ b_z,
                            const float* __restrict__ W_r, const float* __restrict__ b_r,
                            const float* __restrict__ W_h, const float* __restrict__ b_h,
                            const float* __restrict__ W_out, const float* __restrict__ b_out,
                            const float* __restrict__ pre,
                            float* __restrict__ out, Keys keys) {
  __shared__ __align__(16) float h_lds[BM * HD];     // 65536 B (XOR-swizzled chunks)
  __shared__ __align__(16) float wt_l[8 * HD];       //  8192 B
  __shared__ __align__(16) float wout_t[VT * HD];    //  6144 B  [v][k]
  __shared__ unsigned state[BM];                     // code|stopped<<3|len<<4
  __shared__ float tlp[BM];
  // total 80384 B -> 2 blocks/CU

  float4* h4  = (float4*)h_lds;
  float4* wt4 = (float4*)wt_l;
  const float4* pre4 = (const float4*)pre;

  const int tid = threadIdx.x;
  const int rg  = tid >> 4;          // 0..7 (8-row group)
  const int cg  = tid & 15;          // 0..15 (col chunks cg+16j)
  const int b0  = blockIdx.x * BM;

  // stage W_out transposed; init per-row state
  for (int idx = tid; idx < HD * VT; idx += NTH) {
    int k = idx & 255, v = idx >> 8;
    wout_t[v * HD + k] = W_out[k * VT + v];
  }
  if (tid < BM) { state[tid] = 7u; tlp[tid] = 0.f; }

  // stage x tile into chunks 0..31 (swizzled)
  const float4* x4 = (const float4*)x;
#pragma unroll
  for (int s = 0; s < 16; ++s) {
    int f = s * NTH + tid;                  // 2048 float4s
    int row = f >> 5, c4 = f & 31;
    h4[row * 64 + (c4 ^ ((row >> 3) & 7))] = x4[(size_t)(b0 + row) * 32 + c4];
  }

  float4 acc[8][4], z_s[8][4], hold[8][4];

  // ---- encoder: h0 = x @ W_enc + b_enc ----
#pragma unroll
  for (int r = 0; r < 8; ++r)
#pragma unroll
    for (int j = 0; j < 4; ++j) acc[r][j] = make_float4(0.f, 0.f, 0.f, 0.f);
  gemm((const float4*)W_enc, DIN / 8, h4, wt4, tid, rg, cg, acc);
  __syncthreads();  // all A-reads of x done before overwriting with h
#pragma unroll
  for (int j = 0; j < 4; ++j) {
    float4 bb = ((const float4*)b_enc)[cg + 16 * j];
#pragma unroll
    for (int r = 0; r < 8; ++r) {
      float4 o = acc[r][j];
      o.x += bb.x; o.y += bb.y; o.z += bb.z; o.w += bb.w;
      h4[(rg * 8 + r) * 64 + ((cg + 16 * j) ^ rg)] = o;
    }
  }
  // (next gemm's first barrier publishes h)

  for (int t = 0; t < TS; ++t) {
    // ---- z gate: acc stays in regs (z_s) ----
#pragma unroll
    for (int r = 0; r < 8; ++r) {
      unsigned code = state[rg * 8 + r] & 7u;
#pragma unroll
      for (int j = 0; j < 4; ++j) acc[r][j] = pre4[(0 * 8 + code) * 64 + cg + 16 * j];
    }
    gemm((const float4*)(W_z + 256 * HD), HD / 8, h4, wt4, tid, rg, cg, acc);
#pragma unroll
    for (int j = 0; j < 4; ++j) {
      float4 b4 = ((const float4*)b_z)[cg + 16 * j];
#pragma unroll
      for (int r = 0; r < 8; ++r) {
        z_s[r][j].x = sigf(acc[r][j].x + b4.x);
        z_s[r][j].y = sigf(acc[r][j].y + b4.y);
        z_s[r][j].z = sigf(acc[r][j].z + b4.z);
        z_s[r][j].w = sigf(acc[r][j].w + b4.w);
      }
    }
    // ---- r gate: epilogue saves h_old to regs, writes r*h into h ----
#pragma unroll
    for (int r = 0; r < 8; ++r) {
      unsigned code = state[rg * 8 + r] & 7u;
#pragma unroll
      for (int j = 0; j < 4; ++j) acc[r][j] = pre4[(1 * 8 + code) * 64 + cg + 16 * j];
    }
    gemm((const float4*)(W_r + 256 * HD), HD / 8, h4, wt4, tid, rg, cg, acc);
    __syncthreads();  // all A-reads of h done
#pragma unroll
    for (int j = 0; j < 4; ++j) {
      float4 b4 = ((const float4*)b_r)[cg + 16 * j];
#pragma unroll
      for (int r = 0; r < 8; ++r) {
        float4 hv = h4[(rg * 8 + r) * 64 + ((cg + 16 * j) ^ rg)];
        hold[r][j] = hv;
        float4 rh;
        rh.x = sigf(acc[r][j].x + b4.x) * hv.x;
        rh.y = sigf(acc[r][j].y + b4.y) * hv.y;
        rh.z = sigf(acc[r][j].z + b4.z) * hv.z;
        rh.w = sigf(acc[r][j].w + b4.w) * hv.w;
        h4[(rg * 8 + r) * 64 + ((cg + 16 * j) ^ rg)] = rh;
      }
    }
    __syncthreads();  // rh published

    // ---- candidate gate (A = r*h) ----
#pragma unroll
    for (int r = 0; r < 8; ++r) {
      unsigned code = state[rg * 8 + r] & 7u;
#pragma unroll
      for (int j = 0; j < 4; ++j) acc[r][j] = pre4[(2 * 8 + code) * 64 + cg + 16 * j];
    }
    gemm((const float4*)(W_h + 256 * HD), HD / 8, h4, wt4, tid, rg, cg, acc);
    __syncthreads();  // all A-reads of rh done
#pragma unroll
    for (int j = 0; j < 4; ++j) {
      float4 b4 = ((const float4*)b_h)[cg + 16 * j];
#pragma unroll
      for (int r = 0; r < 8; ++r) {
        float4 ht;
        ht.x = tanhf(acc[r][j].x + b4.x);
        ht.y = tanhf(acc[r][j].y + b4.y);
        ht.z = tanhf(acc[r][j].z + b4.z);
        ht.w = tanhf(acc[r][j].w + b4.w);
        float4 z = z_s[r][j], ho = hold[r][j], hn;
        hn.x = (1.0f - z.x) * ho.x + z.x * ht.x;
        hn.y = (1.0f - z.y) * ho.y + z.y * ht.y;
        hn.z = (1.0f - z.z) * ho.z + z.z * ht.z;
        hn.w = (1.0f - z.w) * ho.w + z.w * ht.w;
        h4[(rg * 8 + r) * 64 + ((cg + 16 * j) ^ rg)] = hn;
      }
    }
    __syncthreads();  // h_new visible for logits

    // ---- logits + sampling: 2 lanes per row ----
    {
      const int m = tid >> 1, q = tid & 1, key = (m >> 3) & 7;
      float l[VT] = {0.f, 0.f, 0.f, 0.f, 0.f, 0.f};
      const float4* wo4 = (const float4*)wout_t;
#pragma unroll
      for (int jj = 0; jj < 32; ++jj) {
        int c4a = q * 32 + jj;
        float4 hv = h4[m * 64 + (c4a ^ key)];
#pragma unroll
        for (int v = 0; v < VT; ++v) {
          float4 w = wo4[v * 64 + c4a];
          l[v] += hv.x * w.x + hv.y * w.y + hv.z * w.z + hv.w * w.w;
        }
      }
#pragma unroll
      for (int v = 0; v < VT; ++v) l[v] += __shfl_xor(l[v], 1, 64);
      if (q == 0) {
        const int row = b0 + m;
        unsigned st = state[m];
        if (!(st & 8u)) {
#pragma unroll
          for (int v = 0; v < VT; ++v) l[v] += b_out[v];
          // gumbel-argmax, bit-matching jax.random.categorical
          // (threefry_partitionable: counter (0, j), bits = o0 ^ o1)
          const uint32_t k0 = keys.a[t], k1 = keys.b[t];
          float best = 0.f; int tok = 0;
#pragma unroll
          for (int v = 0; v < VT; ++v) {
            uint32_t j = (uint32_t)row * 6u + (uint32_t)v;
            uint32_t o0, o1;
            tf2x32(k0, k1, 0u, j, o0, o1);
            uint32_t bits = o0 ^ o1;
            float f = __uint_as_float((bits >> 9) | 0x3f800000u) - 1.0f;
            float u = (f > 0.f) ? f : 1.175494350822288e-38f;
            float lg1 = (float)log((double)u);
            float lg2 = (float)log((double)(-lg1));
            float val = l[v] + (-lg2);
            if (v == 0 || val > best) { best = val; tok = v; }
          }
          float lmax = l[0];
#pragma unroll
          for (int v = 1; v < VT; ++v) lmax = fmaxf(lmax, l[v]);
          float s = 0.f;
#pragma unroll
          for (int v = 0; v < VT; ++v) s += expf(l[v] - lmax);
          float lp = (l[tok] - lmax) - logf(s);
          tlp[m] += lp;
          const bool is_stop = (tok == VT - 1);
          unsigned len = ((st >> 4) & 7u) + (is_stop ? 0u : 1u);
#pragma unroll
          for (int v = 0; v < VT; ++v)
            out[(size_t)row * (TS * VT) + t * VT + v] = (v == tok) ? 1.0f : 0.0f;
          state[m] = (unsigned)tok | (is_stop ? 8u : 0u) | (len << 4);
        } else {
#pragma unroll
          for (int v = 0; v < VT; ++v)
            out[(size_t)row * (TS * VT) + t * VT + v] = 0.0f;
          state[m] = 6u | 8u | (st & 0x70u);
        }
      }
    }
    __syncthreads();  // state/tlp visible for next step
  }

  if (tid < BM) {
    const int row = b0 + tid;
    out[(size_t)NB * (TS * VT) + row]      = tlp[tid];
    out[(size_t)NB * (TS * VT) + NB + row] = (float)((state[tid] >> 4) & 7u);
  }
}

extern "C" void kernel_launch(void* const* d_in, const int* in_sizes, int n_in,
                              void* d_out, int out_size, void* d_ws, size_t ws_size,
                              hipStream_t stream) {
  (void)in_sizes; (void)n_in; (void)out_size; (void)ws_size;
  const float* x          = (const float*)d_in[0];
  const float* W_enc      = (const float*)d_in[1];
  const float* b_enc      = (const float*)d_in[2];
  const float* W_embed    = (const float*)d_in[3];
  const float* b_embed    = (const float*)d_in[4];
  const float* W_z        = (const float*)d_in[5];
  const float* b_z        = (const float*)d_in[6];
  const float* W_r        = (const float*)d_in[7];
  const float* b_r        = (const float*)d_in[8];
  const float* W_h        = (const float*)d_in[9];
  const float* b_h        = (const float*)d_in[10];
  const float* W_out      = (const float*)d_in[11];
  const float* b_out      = (const float*)d_in[12];
  const float* start_embed= (const float*)d_in[13];
  float* out = (float*)d_out;
  float* pre = (float*)d_ws;   // 3*8*256 floats = 24 KiB

  pre_kernel<<<24, 256, 0, stream>>>(W_embed, b_embed, start_embed, W_z, W_r, W_h, pre);

  // keys = jax.random.split(jax.random.key(42), 6), partitionable mode
  Keys K;
  for (int t = 0; t < 6; ++t) {
    uint32_t o0, o1;
    tf2x32(0u, 42u, 0u, (uint32_t)t, o0, o1);
    K.a[t] = o0; K.b[t] = o1;
  }

  main_kernel<<<NB / BM, NTH, 0, stream>>>(x, W_enc, b_enc, W_z, b_z, W_r, b_r,
                                           W_h, b_h, W_out, b_out, pre, out, K);
}

// Round 5
// 2479.433 us; speedup vs baseline: 3.8630x; 2.2237x over previous
//
#include <hip/hip_runtime.h>
#include <stdint.h>

// Problem constants
#define NB   131072
#define DIN  128
#define HD   256
#define VT   6
#define TS   6
// Tiling: BM=64 batch rows/block, 256 threads = 4 waves; wave owns M-stripe of 64
// weight-cols; MFMA 16x16x32 bf16, fp32 emulated via exact 3-plane bf16 split
// (hi+mid+lo == fp32 bitwise; 6 products ~2^-31 relative error).
#define BM   64
#define NTH  256

typedef __attribute__((ext_vector_type(8))) short bfrag;   // 8 bf16 (4 VGPRs)
typedef __attribute__((ext_vector_type(4))) short bh4;     // 4 bf16
typedef __attribute__((ext_vector_type(4))) float f32x4;   // MFMA C/D

struct Keys { uint32_t a[6]; uint32_t b[6]; };

// ---- JAX threefry2x32 (20 rounds), bit-exact ----
__host__ __device__ inline void tf2x32(uint32_t k0, uint32_t k1,
                                       uint32_t c0, uint32_t c1,
                                       uint32_t& o0, uint32_t& o1) {
  uint32_t ks2 = k0 ^ k1 ^ 0x1BD11BDAu;
  uint32_t x0 = c0 + k0, x1 = c1 + k1;
#define TFR(d) { x0 += x1; x1 = (x1 << (d)) | (x1 >> (32 - (d))); x1 ^= x0; }
  TFR(13) TFR(15) TFR(26) TFR(6)
  x0 += k1;  x1 += ks2 + 1u;
  TFR(17) TFR(29) TFR(16) TFR(24)
  x0 += ks2; x1 += k0 + 2u;
  TFR(13) TFR(15) TFR(26) TFR(6)
  x0 += k0;  x1 += k1 + 3u;
  TFR(17) TFR(29) TFR(16) TFR(24)
  x0 += k1;  x1 += ks2 + 4u;
  TFR(13) TFR(15) TFR(26) TFR(6)
  x0 += ks2; x1 += k0 + 5u;
#undef TFR
  o0 = x0; o1 = x1;
}

__device__ __forceinline__ unsigned short f2bf(float x) {   // RNE f32->bf16
  uint32_t b = __float_as_uint(x);
  uint32_t r = b + 0x7FFFu + ((b >> 16) & 1u);
  return (unsigned short)(r >> 16);
}
__device__ __forceinline__ float bf2f(unsigned short u) {
  return __uint_as_float(((uint32_t)u) << 16);
}
__device__ __forceinline__ float sigf(float v) { return 1.0f / (1.0f + expf(-v)); }

#define MFMA16(a, b, c) __builtin_amdgcn_mfma_f32_16x16x32_bf16((a), (b), (c), 0, 0, 0)

// 6-product bf16x3: (hi,hi),(hi,mid),(mid,hi),(mid,mid),(hi,lo),(lo,hi)
__device__ __forceinline__ f32x4 prod6(const bfrag A[3], bfrag B0, bfrag B1, bfrag B2,
                                       f32x4 c) {
  c = MFMA16(A[0], B0, c);
  c = MFMA16(A[0], B1, c);
  c = MFMA16(A[1], B0, c);
  c = MFMA16(A[1], B1, c);
  c = MFMA16(A[0], B2, c);
  c = MFMA16(A[2], B0, c);
  return c;
}

// ---- Kernel A: build (a) pre tables f32, (b) W bf16x3 frag buffers in MFMA
// A-layout order: frag idx = ((p*KC + kc)*16 + mt)*512 + lane*8 + j, element
// A[m = mt*16 + (lane&15)][k = kc*32 + (lane>>4)*8 + j] = W[krow0+k][m].
__global__ void pre_kernel(const float* __restrict__ W_enc,
                           const float* __restrict__ W_embed,
                           const float* __restrict__ b_embed,
                           const float* __restrict__ start_embed,
                           const float* __restrict__ W_z,
                           const float* __restrict__ W_r,
                           const float* __restrict__ W_h,
                           float* __restrict__ pre,
                           unsigned short* __restrict__ encf,
                           unsigned short* __restrict__ zf,
                           unsigned short* __restrict__ rf,
                           unsigned short* __restrict__ hf) {
  const int bid = blockIdx.x;
  if (bid < 24) {  // pre tables: codes 0..5 = W_embed[c]+b_embed, 6 = b_embed, 7 = start
    __shared__ float xin[HD];
    const int c = bid & 7, g = bid >> 3, j = threadIdx.x;
    float v;
    if (c < 6)       v = W_embed[c * HD + j] + b_embed[j];
    else if (c == 6) v = b_embed[j];
    else             v = start_embed[j];
    xin[j] = v;
    __syncthreads();
    const float* Wg = (g == 0) ? W_z : (g == 1) ? W_r : W_h;  // top half rows 0..255
    float acc = 0.f;
    for (int k = 0; k < HD; ++k) acc += xin[k] * Wg[k * HD + j];
    pre[(g * 8 + c) * HD + j] = acc;
    return;
  }
  int id = (bid - 24) * 256 + threadIdx.x;   // 0 .. 28671
  const float* src; unsigned short* dst; int kc, mt, lane, KC, krow0;
  if (id < 4096) {            // encoder frags: KC=4 (K=128)
    lane = id & 63; mt = (id >> 6) & 15; kc = id >> 10;
    src = W_enc; dst = encf; KC = 4; krow0 = 0;
  } else {                    // gate frags: KC=8 (K=256), bottom half rows 256..511
    int rem = id - 4096; int g = rem >> 13; int rr = rem & 8191;
    lane = rr & 63; mt = (rr >> 6) & 15; kc = rr >> 10;
    src = (g == 0) ? W_z : (g == 1) ? W_r : W_h;
    dst = (g == 0) ? zf  : (g == 1) ? rf  : hf;
    KC = 8; krow0 = 256;
  }
  const int m  = mt * 16 + (lane & 15);
  const int k0 = kc * 32 + ((lane >> 4) & 3) * 8;
  __align__(16) unsigned short P[3][8];
#pragma unroll
  for (int j = 0; j < 8; ++j) {
    float w = src[(size_t)(krow0 + k0 + j) * HD + m];
    unsigned short h1 = f2bf(w);  float r1 = w - bf2f(h1);
    unsigned short h2 = f2bf(r1); float r2 = r1 - bf2f(h2);
    unsigned short h3 = f2bf(r2);                  // hi+mid+lo == w exactly
    P[0][j] = h1; P[1][j] = h2; P[2][j] = h3;
  }
  for (int p = 0; p < 3; ++p) {
    unsigned short* d = dst + ((size_t)(p * KC + kc) * 16 + mt) * 512 + (size_t)lane * 8;
    *(uint4*)d = *(const uint4*)P[p];
  }
}

// GEMM pass: A = W frags (global/L2, pre-split planes), B = h planes (LDS).
// NG=2 shares B across two A streams (z+r fused).
template<int KC, int NG>
__device__ __forceinline__ void gemm_pass(const unsigned short* __restrict__ f0,
                                          const unsigned short* __restrict__ f1,
                                          const unsigned short* hp_s,
                                          int wave, int lane,
                                          f32x4 acc0[4][4], f32x4 acc1[4][4]) {
  const int ln = lane & 15, qk = lane >> 4;
#pragma unroll 1
  for (int kc = 0; kc < KC; ++kc) {
    bfrag B[3][4];
#pragma unroll
    for (int p = 0; p < 3; ++p)
#pragma unroll
      for (int nt = 0; nt < 4; ++nt)
        B[p][nt] = *(const bfrag*)&hp_s[((p * 32 + kc * 4 + qk) * 64 + nt * 16 + ln) * 8];
#pragma unroll
    for (int mtl = 0; mtl < 4; ++mtl) {
      const int fo = (kc * 16 + wave * 4 + mtl) * 512 + lane * 8;
      bfrag A0[3], A1[3];
#pragma unroll
      for (int p = 0; p < 3; ++p) A0[p] = *(const bfrag*)(f0 + fo + p * (KC * 8192));
      if (NG == 2) {
#pragma unroll
        for (int p = 0; p < 3; ++p) A1[p] = *(const bfrag*)(f1 + fo + p * (KC * 8192));
      }
#pragma unroll
      for (int nt = 0; nt < 4; ++nt) {
        acc0[mtl][nt] = prod6(A0, B[0][nt], B[1][nt], B[2][nt], acc0[mtl][nt]);
        if (NG == 2)
          acc1[mtl][nt] = prod6(A1, B[0][nt], B[1][nt], B[2][nt], acc1[mtl][nt]);
      }
    }
  }
}

// ---- main kernel: persistent per-row-block rollout (h lives as 3 bf16 planes in LDS)
__launch_bounds__(NTH, 1)
__global__ void main_kernel(const float* __restrict__ x,
                            const float* __restrict__ b_enc,
                            const float* __restrict__ b_z,
                            const float* __restrict__ b_r,
                            const float* __restrict__ b_h,
                            const float* __restrict__ W_out,
                            const float* __restrict__ b_out,
                            const float* __restrict__ pre,
                            const unsigned short* __restrict__ encf,
                            const unsigned short* __restrict__ zf,
                            const unsigned short* __restrict__ rf,
                            const unsigned short* __restrict__ hf,
                            float* __restrict__ out, Keys keys) {
  // hp_s: [plane 3][chunk 32][row 64][8 bf16]  (chunk c holds cols 8c..8c+7)
  __shared__ __align__(16) unsigned short hp_s[3 * 32 * 64 * 8];  // 98304 B
  __shared__ __align__(16) float preL[3 * 8 * 256];               // 24576 B
  __shared__ __align__(16) float wout_t[VT * HD];                 //  6144 B
  __shared__ __align__(16) float biasL[3 * 256];                  //  3072 B
  __shared__ unsigned state[BM];
  __shared__ float tlp[BM];
  // total 132,608 B -> 1 block/CU, 4 waves

  const int tid = threadIdx.x;
  const int wave = tid >> 6, lane = tid & 63;
  const int ln = lane & 15, qk = lane >> 4;
  const int b0 = blockIdx.x * BM;

  for (int i = tid; i < VT * HD; i += NTH) {
    int k = i & 255, v = i >> 8;
    wout_t[v * HD + k] = W_out[k * VT + v];
  }
  for (int i = tid; i < 3 * 8 * 256; i += NTH) preL[i] = pre[i];
  for (int i = tid; i < 768; i += NTH) {
    int g = i >> 8;
    biasL[i] = ((g == 0) ? b_z : (g == 1) ? b_r : b_h)[i & 255];
  }
  if (tid < BM) { state[tid] = 7u; tlp[tid] = 0.f; }

  // stage x (B-operand planes), chunks 0..15
  for (int i = tid; i < BM * DIN; i += NTH) {
    int row = i >> 7, k = i & 127;
    float v = x[(size_t)(b0 + row) * DIN + k];
    unsigned short h1 = f2bf(v);  float r1 = v - bf2f(h1);
    unsigned short h2 = f2bf(r1); float r2 = r1 - bf2f(h2);
    int base = ((k >> 3) * 64 + row) * 8 + (k & 7);
    hp_s[base]           = h1;
    hp_s[base + 16384]   = h2;
    hp_s[base + 32768]   = f2bf(r2);
  }
  __syncthreads();

  f32x4 acc0[4][4], acc1[4][4], z_s[4][4], hold[4][4];

  // ---- encoder: h0 = x @ W_enc + b_enc ----
#pragma unroll
  for (int mtl = 0; mtl < 4; ++mtl) {
    int mb = wave * 64 + mtl * 16 + qk * 4;
    f32x4 be = *(const f32x4*)&b_enc[mb];
#pragma unroll
    for (int nt = 0; nt < 4; ++nt) acc0[mtl][nt] = be;
  }
  gemm_pass<4, 1>(encf, nullptr, hp_s, wave, lane, acc0, acc1);
  __syncthreads();  // all x-plane reads done
#pragma unroll
  for (int mtl = 0; mtl < 4; ++mtl) {
    int mb = wave * 64 + mtl * 16 + qk * 4;
    int chunk = mb >> 3, off = mb & 7;
#pragma unroll
    for (int nt = 0; nt < 4; ++nt) {
      int n = nt * 16 + ln;
      bh4 P0, P1, P2;
#pragma unroll
      for (int j = 0; j < 4; ++j) {
        float v = acc0[mtl][nt][j];
        unsigned short h1 = f2bf(v);  float r1 = v - bf2f(h1);
        unsigned short h2 = f2bf(r1); float r2 = r1 - bf2f(h2);
        P0[j] = (short)h1; P1[j] = (short)h2; P2[j] = (short)f2bf(r2);
      }
      *(bh4*)&hp_s[((0 * 32 + chunk) * 64 + n) * 8 + off] = P0;
      *(bh4*)&hp_s[((1 * 32 + chunk) * 64 + n) * 8 + off] = P1;
      *(bh4*)&hp_s[((2 * 32 + chunk) * 64 + n) * 8 + off] = P2;
    }
  }
  __syncthreads();

#pragma unroll 1
  for (int t = 0; t < TS; ++t) {
    // ---- fused z+r (C-init from pre tables; D[m][n]: n=lane&15, m=qk*4+reg) ----
#pragma unroll
    for (int mtl = 0; mtl < 4; ++mtl) {
      int mb = wave * 64 + mtl * 16 + qk * 4;
#pragma unroll
      for (int nt = 0; nt < 4; ++nt) {
        int code = (int)(state[nt * 16 + ln] & 7u);
        acc0[mtl][nt] = *(const f32x4*)&preL[(0 * 8 + code) * 256 + mb];
        acc1[mtl][nt] = *(const f32x4*)&preL[(1 * 8 + code) * 256 + mb];
      }
    }
    gemm_pass<8, 2>(zf, rf, hp_s, wave, lane, acc0, acc1);
    __syncthreads();  // all h-plane reads done
    // zr epilogue: z->regs, h_old->regs (exact plane sum), rh -> planes
#pragma unroll
    for (int mtl = 0; mtl < 4; ++mtl) {
      int mb = wave * 64 + mtl * 16 + qk * 4;
      f32x4 bz4 = *(const f32x4*)&biasL[0 * 256 + mb];
      f32x4 br4 = *(const f32x4*)&biasL[1 * 256 + mb];
      int chunk = mb >> 3, off = mb & 7;
#pragma unroll
      for (int nt = 0; nt < 4; ++nt) {
        int n = nt * 16 + ln;
        bh4 H0 = *(const bh4*)&hp_s[((0 * 32 + chunk) * 64 + n) * 8 + off];
        bh4 H1 = *(const bh4*)&hp_s[((1 * 32 + chunk) * 64 + n) * 8 + off];
        bh4 H2 = *(const bh4*)&hp_s[((2 * 32 + chunk) * 64 + n) * 8 + off];
        f32x4 ho, zv;
        bh4 P0, P1, P2;
#pragma unroll
        for (int j = 0; j < 4; ++j) {
          float hv = bf2f((unsigned short)H0[j]) + bf2f((unsigned short)H1[j])
                   + bf2f((unsigned short)H2[j]);
          ho[j] = hv;
          zv[j] = sigf(acc0[mtl][nt][j] + bz4[j]);
          float rv = sigf(acc1[mtl][nt][j] + br4[j]);
          float rhv = rv * hv;
          unsigned short h1 = f2bf(rhv); float r1 = rhv - bf2f(h1);
          unsigned short h2 = f2bf(r1);  float r2 = r1 - bf2f(h2);
          P0[j] = (short)h1; P1[j] = (short)h2; P2[j] = (short)f2bf(r2);
        }
        z_s[mtl][nt] = zv; hold[mtl][nt] = ho;
        *(bh4*)&hp_s[((0 * 32 + chunk) * 64 + n) * 8 + off] = P0;
        *(bh4*)&hp_s[((1 * 32 + chunk) * 64 + n) * 8 + off] = P1;
        *(bh4*)&hp_s[((2 * 32 + chunk) * 64 + n) * 8 + off] = P2;
      }
    }
    __syncthreads();  // rh planes published

    // ---- candidate gate ----
#pragma unroll
    for (int mtl = 0; mtl < 4; ++mtl) {
      int mb = wave * 64 + mtl * 16 + qk * 4;
#pragma unroll
      for (int nt = 0; nt < 4; ++nt) {
        int code = (int)(state[nt * 16 + ln] & 7u);
        acc0[mtl][nt] = *(const f32x4*)&preL[(2 * 8 + code) * 256 + mb];
      }
    }
    gemm_pass<8, 1>(hf, nullptr, hp_s, wave, lane, acc0, acc1);
    __syncthreads();  // all rh-plane reads done
#pragma unroll
    for (int mtl = 0; mtl < 4; ++mtl) {
      int mb = wave * 64 + mtl * 16 + qk * 4;
      f32x4 bh4v = *(const f32x4*)&biasL[2 * 256 + mb];
      int chunk = mb >> 3, off = mb & 7;
#pragma unroll
      for (int nt = 0; nt < 4; ++nt) {
        int n = nt * 16 + ln;
        f32x4 z = z_s[mtl][nt], ho = hold[mtl][nt];
        bh4 P0, P1, P2;
#pragma unroll
        for (int j = 0; j < 4; ++j) {
          float ht = tanhf(acc0[mtl][nt][j] + bh4v[j]);
          float hn = (1.0f - z[j]) * ho[j] + z[j] * ht;
          unsigned short h1 = f2bf(hn); float r1 = hn - bf2f(h1);
          unsigned short h2 = f2bf(r1); float r2 = r1 - bf2f(h2);
          P0[j] = (short)h1; P1[j] = (short)h2; P2[j] = (short)f2bf(r2);
        }
        *(bh4*)&hp_s[((0 * 32 + chunk) * 64 + n) * 8 + off] = P0;
        *(bh4*)&hp_s[((1 * 32 + chunk) * 64 + n) * 8 + off] = P1;
        *(bh4*)&hp_s[((2 * 32 + chunk) * 64 + n) * 8 + off] = P2;
      }
    }
    __syncthreads();  // h_new planes visible

    // ---- logits + sampling: 4 lanes per row ----
    {
      const int m = tid >> 2, q = tid & 3;
      float l[VT] = {0.f, 0.f, 0.f, 0.f, 0.f, 0.f};
#pragma unroll
      for (int c8 = 0; c8 < 8; ++c8) {
        int chunk = q * 8 + c8;
        bfrag H0 = *(const bfrag*)&hp_s[((0 * 32 + chunk) * 64 + m) * 8];
        bfrag H1 = *(const bfrag*)&hp_s[((1 * 32 + chunk) * 64 + m) * 8];
        bfrag H2 = *(const bfrag*)&hp_s[((2 * 32 + chunk) * 64 + m) * 8];
#pragma unroll
        for (int j = 0; j < 8; ++j) {
          float hv = bf2f((unsigned short)H0[j]) + bf2f((unsigned short)H1[j])
                   + bf2f((unsigned short)H2[j]);
          int k = chunk * 8 + j;
#pragma unroll
          for (int v = 0; v < VT; ++v) l[v] += hv * wout_t[v * HD + k];
        }
      }
#pragma unroll
      for (int v = 0; v < VT; ++v) {
        l[v] += __shfl_xor(l[v], 1, 64);
        l[v] += __shfl_xor(l[v], 2, 64);
      }
      if (q == 0) {
        const int row = b0 + m;
        unsigned st = state[m];
        if (!(st & 8u)) {
#pragma unroll
          for (int v = 0; v < VT; ++v) l[v] += b_out[v];
          // gumbel-argmax, bit-matching jax.random.categorical
          // (threefry_partitionable: counter (0, j), bits = o0 ^ o1)
          const uint32_t k0 = keys.a[t], k1 = keys.b[t];
          float best = 0.f; int tok = 0;
#pragma unroll
          for (int v = 0; v < VT; ++v) {
            uint32_t j = (uint32_t)row * 6u + (uint32_t)v;
            uint32_t o0, o1;
            tf2x32(k0, k1, 0u, j, o0, o1);
            uint32_t bits = o0 ^ o1;
            float f = __uint_as_float((bits >> 9) | 0x3f800000u) - 1.0f;
            float u = (f > 0.f) ? f : 1.175494350822288e-38f;
            float lg1 = (float)log((double)u);
            float lg2 = (float)log((double)(-lg1));
            float val = l[v] + (-lg2);
            if (v == 0 || val > best) { best = val; tok = v; }
          }
          float lmax = l[0];
#pragma unroll
          for (int v = 1; v < VT; ++v) lmax = fmaxf(lmax, l[v]);
          float s = 0.f;
#pragma unroll
          for (int v = 0; v < VT; ++v) s += expf(l[v] - lmax);
          float lp = (l[tok] - lmax) - logf(s);
          tlp[m] += lp;
          const bool is_stop = (tok == VT - 1);
          unsigned len = ((st >> 4) & 7u) + (is_stop ? 0u : 1u);
#pragma unroll
          for (int v = 0; v < VT; ++v)
            out[(size_t)row * (TS * VT) + t * VT + v] = (v == tok) ? 1.0f : 0.0f;
          state[m] = (unsigned)tok | (is_stop ? 8u : 0u) | (len << 4);
        } else {
#pragma unroll
          for (int v = 0; v < VT; ++v)
            out[(size_t)row * (TS * VT) + t * VT + v] = 0.0f;
          state[m] = 6u | 8u | (st & 0x70u);
        }
      }
    }
    __syncthreads();  // state/tlp visible for next step
  }

  if (tid < BM) {
    const int row = b0 + tid;
    out[(size_t)NB * (TS * VT) + row]      = tlp[tid];
    out[(size_t)NB * (TS * VT) + NB + row] = (float)((state[tid] >> 4) & 7u);
  }
}

extern "C" void kernel_launch(void* const* d_in, const int* in_sizes, int n_in,
                              void* d_out, int out_size, void* d_ws, size_t ws_size,
                              hipStream_t stream) {
  (void)in_sizes; (void)n_in; (void)out_size; (void)ws_size;
  const float* x          = (const float*)d_in[0];
  const float* W_enc      = (const float*)d_in[1];
  const float* b_enc      = (const float*)d_in[2];
  const float* W_embed    = (const float*)d_in[3];
  const float* b_embed    = (const float*)d_in[4];
  const float* W_z        = (const float*)d_in[5];
  const float* b_z        = (const float*)d_in[6];
  const float* W_r        = (const float*)d_in[7];
  const float* b_r        = (const float*)d_in[8];
  const float* W_h        = (const float*)d_in[9];
  const float* b_h        = (const float*)d_in[10];
  const float* W_out      = (const float*)d_in[11];
  const float* b_out      = (const float*)d_in[12];
  const float* start_embed= (const float*)d_in[13];
  float* out = (float*)d_out;

  // workspace layout (bytes): pre f32 [0,24576); enc frags [24576,221184);
  // z [221184,614400); r [614400,1007616); h [1007616,1400832)
  float* pre = (float*)d_ws;
  unsigned short* encf = (unsigned short*)((char*)d_ws + 24576);
  unsigned short* zfb  = (unsigned short*)((char*)d_ws + 221184);
  unsigned short* rfb  = (unsigned short*)((char*)d_ws + 614400);
  unsigned short* hfb  = (unsigned short*)((char*)d_ws + 1007616);

  pre_kernel<<<136, 256, 0, stream>>>(W_enc, W_embed, b_embed, start_embed,
                                      W_z, W_r, W_h, pre, encf, zfb, rfb, hfb);

  // keys = jax.random.split(jax.random.key(42), 6), partitionable mode
  Keys K;
  for (int t = 0; t < 6; ++t) {
    uint32_t o0, o1;
    tf2x32(0u, 42u, 0u, (uint32_t)t, o0, o1);
    K.a[t] = o0; K.b[t] = o1;
  }

  main_kernel<<<NB / BM, NTH, 0, stream>>>(x, b_enc, b_z, b_r, b_h, W_out, b_out,
                                           pre, encf, zfb, rfb, hfb, out, K);
}

// Round 6
// 2087.994 us; speedup vs baseline: 4.5872x; 1.1875x over previous
//
#include <hip/hip_runtime.h>
#include <stdint.h>

// Problem constants
#define NB   131072
#define DIN  128
#define HD   256
#define VT   6
#define TS   6
// Tiling: BM=32 batch rows/block, 256 threads = 4 waves (wave owns 64 weight-cols),
// 2 blocks/CU (LDS 57KB). MFMA 16x16x32 bf16; fp32 exact via 3-plane bf16 split.
#define BM   32
#define NTH  256

typedef __attribute__((ext_vector_type(8))) short bfrag;   // 8 bf16 (4 VGPRs)
typedef __attribute__((ext_vector_type(4))) short bh4;     // 4 bf16
typedef __attribute__((ext_vector_type(4))) float f32x4;   // MFMA C/D

struct Keys { uint32_t a[6]; uint32_t b[6]; };

// hp plane layout: [p][kc][nt][lane 64][8] shorts, +16-short pad per (p,kc) block
// (pad staggers kc blocks by 8 banks for the logits stage).
#define HPS(p, kc, nt, ln2, j) ((((p) * 8 + (kc)) * 1040) + (nt) * 512 + (ln2) * 8 + (j))

// ---- JAX threefry2x32 (20 rounds), bit-exact ----
__host__ __device__ inline void tf2x32(uint32_t k0, uint32_t k1,
                                       uint32_t c0, uint32_t c1,
                                       uint32_t& o0, uint32_t& o1) {
  uint32_t ks2 = k0 ^ k1 ^ 0x1BD11BDAu;
  uint32_t x0 = c0 + k0, x1 = c1 + k1;
#define TFR(d) { x0 += x1; x1 = (x1 << (d)) | (x1 >> (32 - (d))); x1 ^= x0; }
  TFR(13) TFR(15) TFR(26) TFR(6)
  x0 += k1;  x1 += ks2 + 1u;
  TFR(17) TFR(29) TFR(16) TFR(24)
  x0 += ks2; x1 += k0 + 2u;
  TFR(13) TFR(15) TFR(26) TFR(6)
  x0 += k0;  x1 += k1 + 3u;
  TFR(17) TFR(29) TFR(16) TFR(24)
  x0 += k1;  x1 += ks2 + 4u;
  TFR(13) TFR(15) TFR(26) TFR(6)
  x0 += ks2; x1 += k0 + 5u;
#undef TFR
  o0 = x0; o1 = x1;
}

__device__ __forceinline__ unsigned short f2bf(float x) {   // RNE f32->bf16
  uint32_t b = __float_as_uint(x);
  uint32_t r = b + 0x7FFFu + ((b >> 16) & 1u);
  return (unsigned short)(r >> 16);
}
__device__ __forceinline__ float bf2f(unsigned short u) {
  return __uint_as_float(((uint32_t)u) << 16);
}
__device__ __forceinline__ float sigf(float v) { return 1.0f / (1.0f + expf(-v)); }

#define MFMA16(a, b, c) __builtin_amdgcn_mfma_f32_16x16x32_bf16((a), (b), (c), 0, 0, 0)

// 6-product bf16x3: (hi,hi),(hi,mid),(mid,hi),(mid,mid),(hi,lo),(lo,hi)
__device__ __forceinline__ f32x4 prod6(const bfrag A[3], bfrag B0, bfrag B1, bfrag B2,
                                       f32x4 c) {
  c = MFMA16(A[0], B0, c);
  c = MFMA16(A[0], B1, c);
  c = MFMA16(A[1], B0, c);
  c = MFMA16(A[1], B1, c);
  c = MFMA16(A[0], B2, c);
  c = MFMA16(A[2], B0, c);
  return c;
}

// ---- Kernel A: (a) pre tables f32 WITH gate bias folded in, (b) W bf16x3 frag
// buffers in MFMA A-layout: ((p*KC + kc)*16 + mt)*512 + lane*8 + j holds
// A[m = mt*16 + (lane&15)][k = kc*32 + (lane>>4)*8 + j] = W[krow0+k][m].
__global__ void pre_kernel(const float* __restrict__ W_enc,
                           const float* __restrict__ W_embed,
                           const float* __restrict__ b_embed,
                           const float* __restrict__ start_embed,
                           const float* __restrict__ W_z, const float* __restrict__ b_z,
                           const float* __restrict__ W_r, const float* __restrict__ b_r,
                           const float* __restrict__ W_h, const float* __restrict__ b_h,
                           float* __restrict__ pre,
                           unsigned short* __restrict__ encf,
                           unsigned short* __restrict__ zf,
                           unsigned short* __restrict__ rf,
                           unsigned short* __restrict__ hf) {
  const int bid = blockIdx.x;
  if (bid < 24) {  // pre tables: codes 0..5 = W_embed[c]+b_embed, 6 = b_embed, 7 = start
    __shared__ float xin[HD];
    const int c = bid & 7, g = bid >> 3, j = threadIdx.x;
    float v;
    if (c < 6)       v = W_embed[c * HD + j] + b_embed[j];
    else if (c == 6) v = b_embed[j];
    else             v = start_embed[j];
    xin[j] = v;
    __syncthreads();
    const float* Wg = (g == 0) ? W_z : (g == 1) ? W_r : W_h;  // top half rows 0..255
    const float* bg = (g == 0) ? b_z : (g == 1) ? b_r : b_h;
    float acc = bg[j];                       // fold gate bias into pre table
    for (int k = 0; k < HD; ++k) acc += xin[k] * Wg[k * HD + j];
    pre[(g * 8 + c) * HD + j] = acc;
    return;
  }
  int id = (bid - 24) * 256 + threadIdx.x;   // 0 .. 28671
  const float* src; unsigned short* dst; int kc, mt, lane, KC, krow0;
  if (id < 4096) {            // encoder frags: KC=4 (K=128)
    lane = id & 63; mt = (id >> 6) & 15; kc = id >> 10;
    src = W_enc; dst = encf; KC = 4; krow0 = 0;
  } else {                    // gate frags: KC=8 (K=256), bottom half rows 256..511
    int rem = id - 4096; int g = rem >> 13; int rr = rem & 8191;
    lane = rr & 63; mt = (rr >> 6) & 15; kc = rr >> 10;
    src = (g == 0) ? W_z : (g == 1) ? W_r : W_h;
    dst = (g == 0) ? zf  : (g == 1) ? rf  : hf;
    KC = 8; krow0 = 256;
  }
  const int m  = mt * 16 + (lane & 15);
  const int k0 = kc * 32 + ((lane >> 4) & 3) * 8;
  __align__(16) unsigned short P[3][8];
#pragma unroll
  for (int j = 0; j < 8; ++j) {
    float w = src[(size_t)(krow0 + k0 + j) * HD + m];
    unsigned short h1 = f2bf(w);  float r1 = w - bf2f(h1);
    unsigned short h2 = f2bf(r1); float r2 = r1 - bf2f(h2);
    P[0][j] = h1; P[1][j] = h2; P[2][j] = f2bf(r2);   // hi+mid+lo == w exactly
  }
  for (int p = 0; p < 3; ++p) {
    unsigned short* d = dst + ((size_t)(p * KC + kc) * 16 + mt) * 512 + (size_t)lane * 8;
    *(uint4*)d = *(const uint4*)P[p];
  }
}

// GEMM pass: A = W frags (global/L2), B = h planes (LDS, conflict-free frag layout).
// NG=2 shares B across two A streams (z+r fused).
template<int KC, int NG>
__device__ __forceinline__ void gemm_pass(const unsigned short* __restrict__ f0,
                                          const unsigned short* __restrict__ f1,
                                          const unsigned short* hp_s,
                                          int wave, int lane,
                                          f32x4 acc0[4][2], f32x4 acc1[4][2]) {
#pragma unroll 1
  for (int kc = 0; kc < KC; ++kc) {
    bfrag B[3][2];
#pragma unroll
    for (int p = 0; p < 3; ++p)
#pragma unroll
      for (int nt = 0; nt < 2; ++nt)
        B[p][nt] = *(const bfrag*)&hp_s[HPS(p, kc, nt, lane, 0)];
#pragma unroll
    for (int mtl = 0; mtl < 4; ++mtl) {
      const int fo = (kc * 16 + wave * 4 + mtl) * 512 + lane * 8;
      bfrag A0[3], A1[3];
#pragma unroll
      for (int p = 0; p < 3; ++p) A0[p] = *(const bfrag*)(f0 + fo + p * (KC * 8192));
      if (NG == 2) {
#pragma unroll
        for (int p = 0; p < 3; ++p) A1[p] = *(const bfrag*)(f1 + fo + p * (KC * 8192));
      }
#pragma unroll
      for (int nt = 0; nt < 2; ++nt) {
        acc0[mtl][nt] = prod6(A0, B[0][nt], B[1][nt], B[2][nt], acc0[mtl][nt]);
        if (NG == 2)
          acc1[mtl][nt] = prod6(A1, B[0][nt], B[1][nt], B[2][nt], acc1[mtl][nt]);
      }
    }
  }
}

// ---- main kernel: persistent per-row-block rollout (h = 3 bf16 planes in LDS)
__launch_bounds__(NTH, 2)
__global__ void main_kernel(const float* __restrict__ x,
                            const float* __restrict__ b_enc,
                            const float* __restrict__ W_out,
                            const float* __restrict__ b_out,
                            const float* __restrict__ pre,
                            const unsigned short* __restrict__ encf,
                            const unsigned short* __restrict__ zf,
                            const unsigned short* __restrict__ rf,
                            const unsigned short* __restrict__ hf,
                            float* __restrict__ out, Keys keys) {
  __shared__ __align__(16) unsigned short hp_s[3 * 8 * 1040];  // 49,920 B
  __shared__ __align__(16) float wout2[VT * 8 * 40];           //  7,680 B
  __shared__ unsigned state[BM];
  __shared__ float tlp[BM];
  // total ~57.9 KB -> 2 blocks/CU (8 waves/CU)

  const int tid = threadIdx.x;
  const int wave = tid >> 6, lane = tid & 63;
  const int ln = lane & 15, qk = lane >> 4;
  const int b0 = blockIdx.x * BM;

  // stage W_out into swizzled chunks: wout2[(v*8+q)*40 + (k&31)], q = k>>5
  for (int i = tid; i < VT * HD; i += NTH) {
    int k = i & 255, v = i >> 8;
    wout2[(v * 8 + (k >> 5)) * 40 + (k & 31)] = W_out[k * VT + v];
  }
  if (tid < BM) { state[tid] = 7u; tlp[tid] = 0.f; }

  // stage x (B-operand planes), kc 0..3
  for (int i = tid; i < BM * DIN; i += NTH) {
    int row = i >> 7, k = i & 127;
    float v = x[(size_t)(b0 + row) * DIN + k];
    unsigned short h1 = f2bf(v);  float r1 = v - bf2f(h1);
    unsigned short h2 = f2bf(r1); float r2 = r1 - bf2f(h2);
    int kc = k >> 5, nt = row >> 4, lp = (row & 15) + 16 * ((k >> 3) & 3), j = k & 7;
    hp_s[HPS(0, kc, nt, lp, j)] = h1;
    hp_s[HPS(1, kc, nt, lp, j)] = h2;
    hp_s[HPS(2, kc, nt, lp, j)] = f2bf(r2);
  }
  __syncthreads();

  f32x4 acc0[4][2], acc1[4][2], z_s[4][2], hold[4][2];

  // ---- encoder: h0 = x @ W_enc + b_enc ----
#pragma unroll
  for (int mtl = 0; mtl < 4; ++mtl) {
    int mb = wave * 64 + mtl * 16 + qk * 4;
    f32x4 be = *(const f32x4*)&b_enc[mb];
#pragma unroll
    for (int nt = 0; nt < 2; ++nt) acc0[mtl][nt] = be;
  }
  gemm_pass<4, 1>(encf, nullptr, hp_s, wave, lane, acc0, acc1);
  __syncthreads();  // all x-plane reads done
#pragma unroll
  for (int mtl = 0; mtl < 4; ++mtl) {
    int mb = wave * 64 + mtl * 16 + qk * 4;
    int kc = mb >> 5, hi2 = (mb >> 3) & 3, j0 = mb & 7;
#pragma unroll
    for (int nt = 0; nt < 2; ++nt) {
      int lp = ln + 16 * hi2;
      bh4 P0, P1, P2;
#pragma unroll
      for (int j = 0; j < 4; ++j) {
        float v = acc0[mtl][nt][j];
        unsigned short h1 = f2bf(v);  float r1 = v - bf2f(h1);
        unsigned short h2 = f2bf(r1); float r2 = r1 - bf2f(h2);
        P0[j] = (short)h1; P1[j] = (short)h2; P2[j] = (short)f2bf(r2);
      }
      *(bh4*)&hp_s[HPS(0, kc, nt, lp, j0)] = P0;
      *(bh4*)&hp_s[HPS(1, kc, nt, lp, j0)] = P1;
      *(bh4*)&hp_s[HPS(2, kc, nt, lp, j0)] = P2;
    }
  }
  __syncthreads();

#pragma unroll 1
  for (int t = 0; t < TS; ++t) {
    // ---- fused z+r (C-init from pre tables incl. bias) ----
#pragma unroll
    for (int mtl = 0; mtl < 4; ++mtl) {
      int mb = wave * 64 + mtl * 16 + qk * 4;
#pragma unroll
      for (int nt = 0; nt < 2; ++nt) {
        int code = (int)(state[nt * 16 + ln] & 7u);
        acc0[mtl][nt] = *(const f32x4*)&pre[(0 * 8 + code) * 256 + mb];
        acc1[mtl][nt] = *(const f32x4*)&pre[(1 * 8 + code) * 256 + mb];
      }
    }
    gemm_pass<8, 2>(zf, rf, hp_s, wave, lane, acc0, acc1);
    __syncthreads();  // all h-plane reads done
#pragma unroll
    for (int mtl = 0; mtl < 4; ++mtl) {
      int mb = wave * 64 + mtl * 16 + qk * 4;
      int kc = mb >> 5, hi2 = (mb >> 3) & 3, j0 = mb & 7;
#pragma unroll
      for (int nt = 0; nt < 2; ++nt) {
        int lp = ln + 16 * hi2;
        bh4 H0 = *(const bh4*)&hp_s[HPS(0, kc, nt, lp, j0)];
        bh4 H1 = *(const bh4*)&hp_s[HPS(1, kc, nt, lp, j0)];
        bh4 H2 = *(const bh4*)&hp_s[HPS(2, kc, nt, lp, j0)];
        f32x4 ho, zv;
        bh4 P0, P1, P2;
#pragma unroll
        for (int j = 0; j < 4; ++j) {
          float hv = bf2f((unsigned short)H0[j]) + bf2f((unsigned short)H1[j])
                   + bf2f((unsigned short)H2[j]);
          ho[j] = hv;
          zv[j] = sigf(acc0[mtl][nt][j]);
          float rhv = sigf(acc1[mtl][nt][j]) * hv;
          unsigned short h1 = f2bf(rhv); float r1 = rhv - bf2f(h1);
          unsigned short h2 = f2bf(r1);  float r2 = r1 - bf2f(h2);
          P0[j] = (short)h1; P1[j] = (short)h2; P2[j] = (short)f2bf(r2);
        }
        z_s[mtl][nt] = zv; hold[mtl][nt] = ho;
        *(bh4*)&hp_s[HPS(0, kc, nt, lp, j0)] = P0;
        *(bh4*)&hp_s[HPS(1, kc, nt, lp, j0)] = P1;
        *(bh4*)&hp_s[HPS(2, kc, nt, lp, j0)] = P2;
      }
    }
    __syncthreads();  // rh planes published

    // ---- candidate gate ----
#pragma unroll
    for (int mtl = 0; mtl < 4; ++mtl) {
      int mb = wave * 64 + mtl * 16 + qk * 4;
#pragma unroll
      for (int nt = 0; nt < 2; ++nt) {
        int code = (int)(state[nt * 16 + ln] & 7u);
        acc0[mtl][nt] = *(const f32x4*)&pre[(2 * 8 + code) * 256 + mb];
      }
    }
    gemm_pass<8, 1>(hf, nullptr, hp_s, wave, lane, acc0, acc1);
    __syncthreads();  // all rh-plane reads done
#pragma unroll
    for (int mtl = 0; mtl < 4; ++mtl) {
      int mb = wave * 64 + mtl * 16 + qk * 4;
      int kc = mb >> 5, hi2 = (mb >> 3) & 3, j0 = mb & 7;
#pragma unroll
      for (int nt = 0; nt < 2; ++nt) {
        int lp = ln + 16 * hi2;
        f32x4 z = z_s[mtl][nt], ho = hold[mtl][nt];
        bh4 P0, P1, P2;
#pragma unroll
        for (int j = 0; j < 4; ++j) {
          float ht = tanhf(acc0[mtl][nt][j]);
          float hn = (1.0f - z[j]) * ho[j] + z[j] * ht;
          unsigned short h1 = f2bf(hn); float r1 = hn - bf2f(h1);
          unsigned short h2 = f2bf(r1); float r2 = r1 - bf2f(h2);
          P0[j] = (short)h1; P1[j] = (short)h2; P2[j] = (short)f2bf(r2);
        }
        *(bh4*)&hp_s[HPS(0, kc, nt, lp, j0)] = P0;
        *(bh4*)&hp_s[HPS(1, kc, nt, lp, j0)] = P1;
        *(bh4*)&hp_s[HPS(2, kc, nt, lp, j0)] = P2;
      }
    }
    __syncthreads();  // h_new planes visible

    // ---- logits + sampling: 8 lanes per row ----
    {
      const int m = tid >> 3, q = tid & 7;
      float l[VT] = {0.f, 0.f, 0.f, 0.f, 0.f, 0.f};
#pragma unroll
      for (int c8 = 0; c8 < 4; ++c8) {
        bfrag H0 = *(const bfrag*)&hp_s[HPS(0, q, m >> 4, (m & 15) + 16 * c8, 0)];
        bfrag H1 = *(const bfrag*)&hp_s[HPS(1, q, m >> 4, (m & 15) + 16 * c8, 0)];
        bfrag H2 = *(const bfrag*)&hp_s[HPS(2, q, m >> 4, (m & 15) + 16 * c8, 0)];
        float hv[8];
#pragma unroll
        for (int j = 0; j < 8; ++j)
          hv[j] = bf2f((unsigned short)H0[j]) + bf2f((unsigned short)H1[j])
                + bf2f((unsigned short)H2[j]);
#pragma unroll
        for (int v = 0; v < VT; ++v) {
          f32x4 w0 = *(const f32x4*)&wout2[(v * 8 + q) * 40 + c8 * 8];
          f32x4 w1 = *(const f32x4*)&wout2[(v * 8 + q) * 40 + c8 * 8 + 4];
          l[v] += hv[0] * w0[0] + hv[1] * w0[1] + hv[2] * w0[2] + hv[3] * w0[3]
                + hv[4] * w1[0] + hv[5] * w1[1] + hv[6] * w1[2] + hv[7] * w1[3];
        }
      }
#pragma unroll
      for (int v = 0; v < VT; ++v) {
        l[v] += __shfl_xor(l[v], 1, 64);
        l[v] += __shfl_xor(l[v], 2, 64);
        l[v] += __shfl_xor(l[v], 4, 64);
      }
      if (q == 0) {
        const int row = b0 + m;
        unsigned st = state[m];
        if (!(st & 8u)) {
#pragma unroll
          for (int v = 0; v < VT; ++v) l[v] += b_out[v];
          // gumbel-argmax, bit-matching jax.random.categorical
          // (threefry_partitionable: counter (0, j), bits = o0 ^ o1)
          const uint32_t k0 = keys.a[t], k1 = keys.b[t];
          float best = 0.f; int tok = 0;
#pragma unroll
          for (int v = 0; v < VT; ++v) {
            uint32_t j = (uint32_t)row * 6u + (uint32_t)v;
            uint32_t o0, o1;
            tf2x32(k0, k1, 0u, j, o0, o1);
            uint32_t bits = o0 ^ o1;
            float f = __uint_as_float((bits >> 9) | 0x3f800000u) - 1.0f;
            float u = (f > 0.f) ? f : 1.175494350822288e-38f;
            float lg1 = (float)log((double)u);
            float lg2 = (float)log((double)(-lg1));
            float val = l[v] + (-lg2);
            if (v == 0 || val > best) { best = val; tok = v; }
          }
          float lmax = l[0];
#pragma unroll
          for (int v = 1; v < VT; ++v) lmax = fmaxf(lmax, l[v]);
          float s = 0.f;
#pragma unroll
          for (int v = 0; v < VT; ++v) s += expf(l[v] - lmax);
          float lp = (l[tok] - lmax) - logf(s);
          tlp[m] += lp;
          const bool is_stop = (tok == VT - 1);
          unsigned len = ((st >> 4) & 7u) + (is_stop ? 0u : 1u);
#pragma unroll
          for (int v = 0; v < VT; ++v)
            out[(size_t)row * (TS * VT) + t * VT + v] = (v == tok) ? 1.0f : 0.0f;
          state[m] = (unsigned)tok | (is_stop ? 8u : 0u) | (len << 4);
        } else {
#pragma unroll
          for (int v = 0; v < VT; ++v)
            out[(size_t)row * (TS * VT) + t * VT + v] = 0.0f;
          state[m] = 6u | 8u | (st & 0x70u);
        }
      }
    }
    __syncthreads();  // state/tlp visible for next step
  }

  if (tid < BM) {
    const int row = b0 + tid;
    out[(size_t)NB * (TS * VT) + row]      = tlp[tid];
    out[(size_t)NB * (TS * VT) + NB + row] = (float)((state[tid] >> 4) & 7u);
  }
}

extern "C" void kernel_launch(void* const* d_in, const int* in_sizes, int n_in,
                              void* d_out, int out_size, void* d_ws, size_t ws_size,
                              hipStream_t stream) {
  (void)in_sizes; (void)n_in; (void)out_size; (void)ws_size;
  const float* x          = (const float*)d_in[0];
  const float* W_enc      = (const float*)d_in[1];
  const float* b_enc      = (const float*)d_in[2];
  const float* W_embed    = (const float*)d_in[3];
  const float* b_embed    = (const float*)d_in[4];
  const float* W_z        = (const float*)d_in[5];
  const float* b_z        = (const float*)d_in[6];
  const float* W_r        = (const float*)d_in[7];
  const float* b_r        = (const float*)d_in[8];
  const float* W_h        = (const float*)d_in[9];
  const float* b_h        = (const float*)d_in[10];
  const float* W_out      = (const float*)d_in[11];
  const float* b_out      = (const float*)d_in[12];
  const float* start_embed= (const float*)d_in[13];
  float* out = (float*)d_out;

  // workspace: pre [0,24576); enc frags [24576,221184); z [221184,614400);
  // r [614400,1007616); h [1007616,1400832)
  float* pre = (float*)d_ws;
  unsigned short* encf = (unsigned short*)((char*)d_ws + 24576);
  unsigned short* zfb  = (unsigned short*)((char*)d_ws + 221184);
  unsigned short* rfb  = (unsigned short*)((char*)d_ws + 614400);
  unsigned short* hfb  = (unsigned short*)((char*)d_ws + 1007616);

  pre_kernel<<<136, 256, 0, stream>>>(W_enc, W_embed, b_embed, start_embed,
                                      W_z, b_z, W_r, b_r, W_h, b_h,
                                      pre, encf, zfb, rfb, hfb);

  // keys = jax.random.split(jax.random.key(42), 6), partitionable mode
  Keys K;
  for (int t = 0; t < 6; ++t) {
    uint32_t o0, o1;
    tf2x32(0u, 42u, 0u, (uint32_t)t, o0, o1);
    K.a[t] = o0; K.b[t] = o1;
  }

  main_kernel<<<NB / BM, NTH, 0, stream>>>(x, b_enc, W_out, b_out,
                                           pre, encf, zfb, rfb, hfb, out, K);
}

// Round 7
// 2032.835 us; speedup vs baseline: 4.7117x; 1.0271x over previous
//
#include <hip/hip_runtime.h>
#include <stdint.h>

// Problem constants
#define NB   131072
#define DIN  128
#define HD   256
#define VT   6
#define TS   6
// Tiling: BM=64 batch rows/block, 512 threads = 8 waves (wave owns 32 weight-cols,
// all 64 batch rows), 1 block/CU. MFMA 16x16x32 bf16; fp32 exact via 3-plane split.
#define BM   64
#define NTH  512

typedef __attribute__((ext_vector_type(8))) short bfrag;   // 8 bf16 (4 VGPRs)
typedef __attribute__((ext_vector_type(4))) short bh4;     // 4 bf16
typedef __attribute__((ext_vector_type(4))) float f32x4;   // MFMA C/D

struct Keys { uint32_t a[6]; uint32_t b[6]; };

// hp plane layout: [p][kc][nt 4][lane 64][8] shorts, +16-short pad per (p,kc) block.
#define HPS(p, kc, nt, lp, j) ((((p) * 8 + (kc)) * 2064) + (nt) * 512 + (lp) * 8 + (j))

// ---- JAX threefry2x32 (20 rounds), bit-exact ----
__host__ __device__ inline void tf2x32(uint32_t k0, uint32_t k1,
                                       uint32_t c0, uint32_t c1,
                                       uint32_t& o0, uint32_t& o1) {
  uint32_t ks2 = k0 ^ k1 ^ 0x1BD11BDAu;
  uint32_t x0 = c0 + k0, x1 = c1 + k1;
#define TFR(d) { x0 += x1; x1 = (x1 << (d)) | (x1 >> (32 - (d))); x1 ^= x0; }
  TFR(13) TFR(15) TFR(26) TFR(6)
  x0 += k1;  x1 += ks2 + 1u;
  TFR(17) TFR(29) TFR(16) TFR(24)
  x0 += ks2; x1 += k0 + 2u;
  TFR(13) TFR(15) TFR(26) TFR(6)
  x0 += k0;  x1 += k1 + 3u;
  TFR(17) TFR(29) TFR(16) TFR(24)
  x0 += k1;  x1 += ks2 + 4u;
  TFR(13) TFR(15) TFR(26) TFR(6)
  x0 += ks2; x1 += k0 + 5u;
#undef TFR
  o0 = x0; o1 = x1;
}

__device__ __forceinline__ unsigned short f2bf(float x) {   // RNE f32->bf16
  uint32_t b = __float_as_uint(x);
  uint32_t r = b + 0x7FFFu + ((b >> 16) & 1u);
  return (unsigned short)(r >> 16);
}
__device__ __forceinline__ float bf2f(unsigned short u) {
  return __uint_as_float(((uint32_t)u) << 16);
}
__device__ __forceinline__ float sigf(float v) { return 1.0f / (1.0f + expf(-v)); }

#define MFMA16(a, b, c) __builtin_amdgcn_mfma_f32_16x16x32_bf16((a), (b), (c), 0, 0, 0)

// 6-product bf16x3: (hi,hi),(hi,mid),(mid,hi),(mid,mm),(hi,lo),(lo,hi) — order fixed.
__device__ __forceinline__ f32x4 prod6(const bfrag A[3], bfrag B0, bfrag B1, bfrag B2,
                                       f32x4 c) {
  c = MFMA16(A[0], B0, c);
  c = MFMA16(A[0], B1, c);
  c = MFMA16(A[1], B0, c);
  c = MFMA16(A[1], B1, c);
  c = MFMA16(A[0], B2, c);
  c = MFMA16(A[2], B0, c);
  return c;
}

// ---- Kernel A: (a) pre tables f32 WITH gate bias folded, (b) W bf16x3 frags in MFMA
// A-layout: ((p*KC + kc)*16 + mt)*512 + lane*8 + j holds
// A[m = mt*16 + (lane&15)][k = kc*32 + (lane>>4)*8 + j] = W[krow0+k][m].
__global__ void pre_kernel(const float* __restrict__ W_enc,
                           const float* __restrict__ W_embed,
                           const float* __restrict__ b_embed,
                           const float* __restrict__ start_embed,
                           const float* __restrict__ W_z, const float* __restrict__ b_z,
                           const float* __restrict__ W_r, const float* __restrict__ b_r,
                           const float* __restrict__ W_h, const float* __restrict__ b_h,
                           float* __restrict__ pre,
                           unsigned short* __restrict__ encf,
                           unsigned short* __restrict__ zf,
                           unsigned short* __restrict__ rf,
                           unsigned short* __restrict__ hf) {
  const int bid = blockIdx.x;
  if (bid < 24) {  // pre tables: codes 0..5 = W_embed[c]+b_embed, 6 = b_embed, 7 = start
    __shared__ float xin[HD];
    const int c = bid & 7, g = bid >> 3, j = threadIdx.x;
    float v;
    if (c < 6)       v = W_embed[c * HD + j] + b_embed[j];
    else if (c == 6) v = b_embed[j];
    else             v = start_embed[j];
    xin[j] = v;
    __syncthreads();
    const float* Wg = (g == 0) ? W_z : (g == 1) ? W_r : W_h;  // top half rows 0..255
    const float* bg = (g == 0) ? b_z : (g == 1) ? b_r : b_h;
    float acc = bg[j];                       // fold gate bias into pre table
    for (int k = 0; k < HD; ++k) acc += xin[k] * Wg[k * HD + j];
    pre[(g * 8 + c) * HD + j] = acc;
    return;
  }
  int id = (bid - 24) * 256 + threadIdx.x;   // 0 .. 28671
  const float* src; unsigned short* dst; int kc, mt, lane, KC, krow0;
  if (id < 4096) {            // encoder frags: KC=4 (K=128)
    lane = id & 63; mt = (id >> 6) & 15; kc = id >> 10;
    src = W_enc; dst = encf; KC = 4; krow0 = 0;
  } else {                    // gate frags: KC=8 (K=256), bottom half rows 256..511
    int rem = id - 4096; int g = rem >> 13; int rr = rem & 8191;
    lane = rr & 63; mt = (rr >> 6) & 15; kc = rr >> 10;
    src = (g == 0) ? W_z : (g == 1) ? W_r : W_h;
    dst = (g == 0) ? zf  : (g == 1) ? rf  : hf;
    KC = 8; krow0 = 256;
  }
  const int m  = mt * 16 + (lane & 15);
  const int k0 = kc * 32 + ((lane >> 4) & 3) * 8;
  __align__(16) unsigned short P[3][8];
#pragma unroll
  for (int j = 0; j < 8; ++j) {
    float w = src[(size_t)(krow0 + k0 + j) * HD + m];
    unsigned short h1 = f2bf(w);  float r1 = w - bf2f(h1);
    unsigned short h2 = f2bf(r1); float r2 = r1 - bf2f(h2);
    P[0][j] = h1; P[1][j] = h2; P[2][j] = f2bf(r2);   // hi+mid+lo == w exactly
  }
  for (int p = 0; p < 3; ++p) {
    unsigned short* d = dst + ((size_t)(p * KC + kc) * 16 + mt) * 512 + (size_t)lane * 8;
    *(uint4*)d = *(const uint4*)P[p];
  }
}

// GEMM pass: A = W frags (global/L2), B = h planes (LDS). Wave owns mt = wave*2+mtl.
// NG=2 shares B across two A streams (z+r fused).
template<int KC, int NG>
__device__ __forceinline__ void gemm_pass(const unsigned short* __restrict__ f0,
                                          const unsigned short* __restrict__ f1,
                                          const unsigned short* hp_s,
                                          int wave, int lane,
                                          f32x4 acc0[2][4], f32x4 acc1[2][4]) {
#pragma unroll 1
  for (int kc = 0; kc < KC; ++kc) {
    bfrag B[3][4];
#pragma unroll
    for (int p = 0; p < 3; ++p)
#pragma unroll
      for (int nt = 0; nt < 4; ++nt)
        B[p][nt] = *(const bfrag*)&hp_s[HPS(p, kc, nt, lane, 0)];
#pragma unroll
    for (int mtl = 0; mtl < 2; ++mtl) {
      const int fo = (kc * 16 + wave * 2 + mtl) * 512 + lane * 8;
      bfrag A0[3], A1[3];
#pragma unroll
      for (int p = 0; p < 3; ++p) A0[p] = *(const bfrag*)(f0 + fo + p * (KC * 8192));
      if (NG == 2) {
#pragma unroll
        for (int p = 0; p < 3; ++p) A1[p] = *(const bfrag*)(f1 + fo + p * (KC * 8192));
      }
#pragma unroll
      for (int nt = 0; nt < 4; ++nt) {
        acc0[mtl][nt] = prod6(A0, B[0][nt], B[1][nt], B[2][nt], acc0[mtl][nt]);
        if (NG == 2)
          acc1[mtl][nt] = prod6(A1, B[0][nt], B[1][nt], B[2][nt], acc1[mtl][nt]);
      }
    }
  }
}

// ---- main kernel: persistent per-row-block rollout; h_old persists in registers
__launch_bounds__(NTH, 2)
__global__ void main_kernel(const float* __restrict__ x,
                            const float* __restrict__ b_enc,
                            const float* __restrict__ W_out,
                            const float* __restrict__ b_out,
                            const float* __restrict__ pre,
                            const unsigned short* __restrict__ encf,
                            const unsigned short* __restrict__ zf,
                            const unsigned short* __restrict__ rf,
                            const unsigned short* __restrict__ hf,
                            float* __restrict__ out, Keys keys) {
  __shared__ __align__(16) unsigned short hp_s[3 * 8 * 2064];  // 99,072 B
  __shared__ __align__(16) float wout2[VT * 8 * 40];           //  7,680 B
  __shared__ float boutL[8];
  __shared__ unsigned state[BM];
  __shared__ float tlp[BM];
  // total ~107.3 KB -> 1 block/CU, 8 waves

  const int tid = threadIdx.x;
  const int wave = tid >> 6, lane = tid & 63;
  const int ln = lane & 15, qk = lane >> 4;
  const int b0 = blockIdx.x * BM;

  // stage W_out into swizzled chunks: wout2[(v*8+q)*40 + (k&31)], q = k>>5
  for (int i = tid; i < VT * HD; i += NTH) {
    int k = i & 255, v = i >> 8;
    wout2[(v * 8 + (k >> 5)) * 40 + (k & 31)] = W_out[k * VT + v];
  }
  if (tid < 8) boutL[tid] = (tid < VT) ? b_out[tid] : 0.f;
  if (tid < BM) { state[tid] = 7u; tlp[tid] = 0.f; }

  // stage x (B-operand planes), kc 0..3
  for (int i = tid; i < BM * DIN; i += NTH) {
    int row = i >> 7, k = i & 127;
    float v = x[(size_t)(b0 + row) * DIN + k];
    unsigned short h1 = f2bf(v);  float r1 = v - bf2f(h1);
    unsigned short h2 = f2bf(r1); float r2 = r1 - bf2f(h2);
    int kc = k >> 5, nt = row >> 4, lp = (row & 15) + 16 * ((k >> 3) & 3), j = k & 7;
    hp_s[HPS(0, kc, nt, lp, j)] = h1;
    hp_s[HPS(1, kc, nt, lp, j)] = h2;
    hp_s[HPS(2, kc, nt, lp, j)] = f2bf(r2);
  }
  __syncthreads();

  f32x4 acc0[2][4], acc1[2][4], z_s[2][4], hold[2][4];

  // ---- encoder: h0 = x @ W_enc + b_enc ----
#pragma unroll
  for (int mtl = 0; mtl < 2; ++mtl) {
    int mb = (wave * 2 + mtl) * 16 + qk * 4;
    f32x4 be = *(const f32x4*)&b_enc[mb];
#pragma unroll
    for (int nt = 0; nt < 4; ++nt) acc0[mtl][nt] = be;
  }
  gemm_pass<4, 1>(encf, nullptr, hp_s, wave, lane, acc0, acc1);
  __syncthreads();  // all x-plane reads done
#pragma unroll
  for (int mtl = 0; mtl < 2; ++mtl) {
    int mb = (wave * 2 + mtl) * 16 + qk * 4;
    int kc = mb >> 5, hi2 = (mb >> 3) & 3, j0 = mb & 7, lp = ln + 16 * hi2;
#pragma unroll
    for (int nt = 0; nt < 4; ++nt) {
      f32x4 o = acc0[mtl][nt];
      hold[mtl][nt] = o;                 // h_old lives in registers from here on
      bh4 P0, P1, P2;
#pragma unroll
      for (int j = 0; j < 4; ++j) {
        float v = o[j];
        unsigned short h1 = f2bf(v);  float r1 = v - bf2f(h1);
        unsigned short h2 = f2bf(r1); float r2 = r1 - bf2f(h2);
        P0[j] = (short)h1; P1[j] = (short)h2; P2[j] = (short)f2bf(r2);
      }
      *(bh4*)&hp_s[HPS(0, kc, nt, lp, j0)] = P0;
      *(bh4*)&hp_s[HPS(1, kc, nt, lp, j0)] = P1;
      *(bh4*)&hp_s[HPS(2, kc, nt, lp, j0)] = P2;
    }
  }
  __syncthreads();

#pragma unroll 1
  for (int t = 0; t < TS; ++t) {
    // ---- fused z+r (C-init from pre tables incl. bias) ----
#pragma unroll
    for (int mtl = 0; mtl < 2; ++mtl) {
      int mb = (wave * 2 + mtl) * 16 + qk * 4;
#pragma unroll
      for (int nt = 0; nt < 4; ++nt) {
        int code = (int)(state[nt * 16 + ln] & 7u);
        acc0[mtl][nt] = *(const f32x4*)&pre[(0 * 8 + code) * 256 + mb];
        acc1[mtl][nt] = *(const f32x4*)&pre[(1 * 8 + code) * 256 + mb];
      }
    }
    gemm_pass<8, 2>(zf, rf, hp_s, wave, lane, acc0, acc1);
    __syncthreads();  // all h-plane reads done
#pragma unroll
    for (int mtl = 0; mtl < 2; ++mtl) {
      int mb = (wave * 2 + mtl) * 16 + qk * 4;
      int kc = mb >> 5, hi2 = (mb >> 3) & 3, j0 = mb & 7, lp = ln + 16 * hi2;
#pragma unroll
      for (int nt = 0; nt < 4; ++nt) {
        f32x4 ho = hold[mtl][nt];        // register h_old (bitwise = plane sum)
        f32x4 zv;
        bh4 P0, P1, P2;
#pragma unroll
        for (int j = 0; j < 4; ++j) {
          zv[j] = sigf(acc0[mtl][nt][j]);
          float rhv = sigf(acc1[mtl][nt][j]) * ho[j];
          unsigned short h1 = f2bf(rhv); float r1 = rhv - bf2f(h1);
          unsigned short h2 = f2bf(r1);  float r2 = r1 - bf2f(h2);
          P0[j] = (short)h1; P1[j] = (short)h2; P2[j] = (short)f2bf(r2);
        }
        z_s[mtl][nt] = zv;
        *(bh4*)&hp_s[HPS(0, kc, nt, lp, j0)] = P0;
        *(bh4*)&hp_s[HPS(1, kc, nt, lp, j0)] = P1;
        *(bh4*)&hp_s[HPS(2, kc, nt, lp, j0)] = P2;
      }
    }
    __syncthreads();  // rh planes published

    // ---- candidate gate ----
#pragma unroll
    for (int mtl = 0; mtl < 2; ++mtl) {
      int mb = (wave * 2 + mtl) * 16 + qk * 4;
#pragma unroll
      for (int nt = 0; nt < 4; ++nt) {
        int code = (int)(state[nt * 16 + ln] & 7u);
        acc0[mtl][nt] = *(const f32x4*)&pre[(2 * 8 + code) * 256 + mb];
      }
    }
    gemm_pass<8, 1>(hf, nullptr, hp_s, wave, lane, acc0, acc1);
    __syncthreads();  // all rh-plane reads done
#pragma unroll
    for (int mtl = 0; mtl < 2; ++mtl) {
      int mb = (wave * 2 + mtl) * 16 + qk * 4;
      int kc = mb >> 5, hi2 = (mb >> 3) & 3, j0 = mb & 7, lp = ln + 16 * hi2;
#pragma unroll
      for (int nt = 0; nt < 4; ++nt) {
        f32x4 z = z_s[mtl][nt], ho = hold[mtl][nt], hn;
        bh4 P0, P1, P2;
#pragma unroll
        for (int j = 0; j < 4; ++j) {
          float ht = tanhf(acc0[mtl][nt][j]);
          hn[j] = (1.0f - z[j]) * ho[j] + z[j] * ht;
          unsigned short h1 = f2bf(hn[j]); float r1 = hn[j] - bf2f(h1);
          unsigned short h2 = f2bf(r1);    float r2 = r1 - bf2f(h2);
          P0[j] = (short)h1; P1[j] = (short)h2; P2[j] = (short)f2bf(r2);
        }
        hold[mtl][nt] = hn;              // persists to next step
        *(bh4*)&hp_s[HPS(0, kc, nt, lp, j0)] = P0;
        *(bh4*)&hp_s[HPS(1, kc, nt, lp, j0)] = P1;
        *(bh4*)&hp_s[HPS(2, kc, nt, lp, j0)] = P2;
      }
    }
    __syncthreads();  // h_new planes visible for logits

    // ---- logits + sampling: 8 lanes per row, gumbel spread across 6 lanes ----
    {
      const int m = tid >> 3, q = tid & 7;
      float l[VT] = {0.f, 0.f, 0.f, 0.f, 0.f, 0.f};
#pragma unroll
      for (int c8 = 0; c8 < 4; ++c8) {
        bfrag H0 = *(const bfrag*)&hp_s[HPS(0, q, m >> 4, (m & 15) + 16 * c8, 0)];
        bfrag H1 = *(const bfrag*)&hp_s[HPS(1, q, m >> 4, (m & 15) + 16 * c8, 0)];
        bfrag H2 = *(const bfrag*)&hp_s[HPS(2, q, m >> 4, (m & 15) + 16 * c8, 0)];
        float hv[8];
#pragma unroll
        for (int j = 0; j < 8; ++j)
          hv[j] = bf2f((unsigned short)H0[j]) + bf2f((unsigned short)H1[j])
                + bf2f((unsigned short)H2[j]);
#pragma unroll
        for (int v = 0; v < VT; ++v) {
          f32x4 w0 = *(const f32x4*)&wout2[(v * 8 + q) * 40 + c8 * 8];
          f32x4 w1 = *(const f32x4*)&wout2[(v * 8 + q) * 40 + c8 * 8 + 4];
          l[v] += hv[0] * w0[0] + hv[1] * w0[1] + hv[2] * w0[2] + hv[3] * w0[3]
                + hv[4] * w1[0] + hv[5] * w1[1] + hv[6] * w1[2] + hv[7] * w1[3];
        }
      }
#pragma unroll
      for (int v = 0; v < VT; ++v) {
        l[v] += __shfl_xor(l[v], 1, 64);
        l[v] += __shfl_xor(l[v], 2, 64);
        l[v] += __shfl_xor(l[v], 4, 64);
      }
      // distributed gumbel: lane q<6 handles vocab v=q (identical op sequence)
      const int row = b0 + m;
      const int vq = (q < VT) ? q : 0;
      float lq = l[vq] + boutL[vq];
      {
        uint32_t j = (uint32_t)row * 6u + (uint32_t)vq;
        uint32_t o0, o1;
        tf2x32(keys.a[t], keys.b[t], 0u, j, o0, o1);
        uint32_t bits = o0 ^ o1;
        float f = __uint_as_float((bits >> 9) | 0x3f800000u) - 1.0f;
        float u = (f > 0.f) ? f : 1.175494350822288e-38f;
        float lg1 = (float)log((double)u);
        float lg2 = (float)log((double)(-lg1));
        lq = lq + (-lg2);
      }
      float vv[VT];
      const int lbase = lane & ~7;
#pragma unroll
      for (int v = 0; v < VT; ++v) vv[v] = __shfl(lq, lbase + v, 64);
      if (q == 0) {
        unsigned st = state[m];
        if (!(st & 8u)) {
#pragma unroll
          for (int v = 0; v < VT; ++v) l[v] += boutL[v];
          float best = 0.f; int tok = 0;
#pragma unroll
          for (int v = 0; v < VT; ++v)
            if (v == 0 || vv[v] > best) { best = vv[v]; tok = v; }
          float lmax = l[0];
#pragma unroll
          for (int v = 1; v < VT; ++v) lmax = fmaxf(lmax, l[v]);
          float s = 0.f;
#pragma unroll
          for (int v = 0; v < VT; ++v) s += expf(l[v] - lmax);
          float lp = (l[tok] - lmax) - logf(s);
          tlp[m] += lp;
          const bool is_stop = (tok == VT - 1);
          unsigned len = ((st >> 4) & 7u) + (is_stop ? 0u : 1u);
#pragma unroll
          for (int v = 0; v < VT; ++v)
            out[(size_t)row * (TS * VT) + t * VT + v] = (v == tok) ? 1.0f : 0.0f;
          state[m] = (unsigned)tok | (is_stop ? 8u : 0u) | (len << 4);
        } else {
#pragma unroll
          for (int v = 0; v < VT; ++v)
            out[(size_t)row * (TS * VT) + t * VT + v] = 0.0f;
          state[m] = 6u | 8u | (st & 0x70u);
        }
      }
    }
    __syncthreads();  // state/tlp visible for next step
  }

  if (tid < BM) {
    const int row = b0 + tid;
    out[(size_t)NB * (TS * VT) + row]      = tlp[tid];
    out[(size_t)NB * (TS * VT) + NB + row] = (float)((state[tid] >> 4) & 7u);
  }
}

extern "C" void kernel_launch(void* const* d_in, const int* in_sizes, int n_in,
                              void* d_out, int out_size, void* d_ws, size_t ws_size,
                              hipStream_t stream) {
  (void)in_sizes; (void)n_in; (void)out_size; (void)ws_size;
  const float* x          = (const float*)d_in[0];
  const float* W_enc      = (const float*)d_in[1];
  const float* b_enc      = (const float*)d_in[2];
  const float* W_embed    = (const float*)d_in[3];
  const float* b_embed    = (const float*)d_in[4];
  const float* W_z        = (const float*)d_in[5];
  const float* b_z        = (const float*)d_in[6];
  const float* W_r        = (const float*)d_in[7];
  const float* b_r        = (const float*)d_in[8];
  const float* W_h        = (const float*)d_in[9];
  const float* b_h        = (const float*)d_in[10];
  const float* W_out      = (const float*)d_in[11];
  const float* b_out      = (const float*)d_in[12];
  const float* start_embed= (const float*)d_in[13];
  float* out = (float*)d_out;

  // workspace: pre [0,24576); enc frags [24576,221184); z [221184,614400);
  // r [614400,1007616); h [1007616,1400832)
  float* pre = (float*)d_ws;
  unsigned short* encf = (unsigned short*)((char*)d_ws + 24576);
  unsigned short* zfb  = (unsigned short*)((char*)d_ws + 221184);
  unsigned short* rfb  = (unsigned short*)((char*)d_ws + 614400);
  unsigned short* hfb  = (unsigned short*)((char*)d_ws + 1007616);

  pre_kernel<<<136, 256, 0, stream>>>(W_enc, W_embed, b_embed, start_embed,
                                      W_z, b_z, W_r, b_r, W_h, b_h,
                                      pre, encf, zfb, rfb, hfb);

  // keys = jax.random.split(jax.random.key(42), 6), partitionable mode
  Keys K;
  for (int t = 0; t < 6; ++t) {
    uint32_t o0, o1;
    tf2x32(0u, 42u, 0u, (uint32_t)t, o0, o1);
    K.a[t] = o0; K.b[t] = o1;
  }

  main_kernel<<<NB / BM, NTH, 0, stream>>>(x, b_enc, W_out, b_out,
                                           pre, encf, zfb, rfb, hfb, out, K);
}

// Round 8
// 1916.198 us; speedup vs baseline: 4.9985x; 1.0609x over previous
//
#include <hip/hip_runtime.h>
#include <stdint.h>

// Problem constants
#define NB   131072
#define DIN  128
#define HD   256
#define VT   6
#define TS   6
// Tiling: BM=32 rows/block, 256 threads = 4 waves (wave owns 64 weight-cols),
// 2 blocks/CU. MFMA 16x16x32 bf16; fp32 exact via 3-plane bf16 split (6 products).
#define BM   32
#define NTH  256

typedef __attribute__((ext_vector_type(8))) short bfrag;   // 8 bf16 (4 VGPRs)
typedef __attribute__((ext_vector_type(4))) short bh4;     // 4 bf16
typedef __attribute__((ext_vector_type(4))) float f32x4;   // MFMA C/D

struct Keys { uint32_t a[6]; uint32_t b[6]; };

// hp plane layout: [p][kc][nt 2][lane 64][8] shorts, +16-short pad per (p,kc) block.
#define HPS(p, kc, nt, lp, j) ((((p) * 8 + (kc)) * 1040) + (nt) * 512 + (lp) * 8 + (j))

// ---- JAX threefry2x32 (20 rounds), bit-exact ----
__host__ __device__ inline void tf2x32(uint32_t k0, uint32_t k1,
                                       uint32_t c0, uint32_t c1,
                                       uint32_t& o0, uint32_t& o1) {
  uint32_t ks2 = k0 ^ k1 ^ 0x1BD11BDAu;
  uint32_t x0 = c0 + k0, x1 = c1 + k1;
#define TFR(d) { x0 += x1; x1 = (x1 << (d)) | (x1 >> (32 - (d))); x1 ^= x0; }
  TFR(13) TFR(15) TFR(26) TFR(6)
  x0 += k1;  x1 += ks2 + 1u;
  TFR(17) TFR(29) TFR(16) TFR(24)
  x0 += ks2; x1 += k0 + 2u;
  TFR(13) TFR(15) TFR(26) TFR(6)
  x0 += k0;  x1 += k1 + 3u;
  TFR(17) TFR(29) TFR(16) TFR(24)
  x0 += k1;  x1 += ks2 + 4u;
  TFR(13) TFR(15) TFR(26) TFR(6)
  x0 += ks2; x1 += k0 + 5u;
#undef TFR
  o0 = x0; o1 = x1;
}

__device__ __forceinline__ unsigned short f2bf(float x) {   // RNE f32->bf16
  uint32_t b = __float_as_uint(x);
  uint32_t r = b + 0x7FFFu + ((b >> 16) & 1u);
  return (unsigned short)(r >> 16);
}
__device__ __forceinline__ float bf2f(unsigned short u) {
  return __uint_as_float(((uint32_t)u) << 16);
}
__device__ __forceinline__ float sigf(float v) { return 1.0f / (1.0f + expf(-v)); }

#define MFMA16(a, b, c) __builtin_amdgcn_mfma_f32_16x16x32_bf16((a), (b), (c), 0, 0, 0)

// 6-product bf16x3: (hi,hi),(hi,mid),(mid,hi),(mid,mid),(hi,lo),(lo,hi)
__device__ __forceinline__ f32x4 prod6(const bfrag A[3], bfrag B0, bfrag B1, bfrag B2,
                                       f32x4 c) {
  c = MFMA16(A[0], B0, c);
  c = MFMA16(A[0], B1, c);
  c = MFMA16(A[1], B0, c);
  c = MFMA16(A[1], B1, c);
  c = MFMA16(A[0], B2, c);
  c = MFMA16(A[2], B0, c);
  return c;
}

// ---- Kernel A: pre tables (gate bias folded), W frags, W_out frags ----
// A-layout: ((p*KC + kc)*16 + mt)*512 + lane*8 + j holds
// A[m = mt*16 + (lane&15)][k = kc*32 + (lane>>4)*8 + j] = W[krow0+k][m].
__global__ void pre_kernel(const float* __restrict__ W_enc,
                           const float* __restrict__ W_embed,
                           const float* __restrict__ b_embed,
                           const float* __restrict__ start_embed,
                           const float* __restrict__ W_z, const float* __restrict__ b_z,
                           const float* __restrict__ W_r, const float* __restrict__ b_r,
                           const float* __restrict__ W_h, const float* __restrict__ b_h,
                           const float* __restrict__ W_out,
                           float* __restrict__ pre,
                           unsigned short* __restrict__ encf,
                           unsigned short* __restrict__ zf,
                           unsigned short* __restrict__ rf,
                           unsigned short* __restrict__ hf,
                           unsigned short* __restrict__ woutf) {
  const int bid = blockIdx.x;
  if (bid < 24) {  // pre tables: codes 0..5 = W_embed[c]+b_embed, 6 = b_embed, 7 = start
    __shared__ float xin[HD];
    const int c = bid & 7, g = bid >> 3, j = threadIdx.x;
    float v;
    if (c < 6)       v = W_embed[c * HD + j] + b_embed[j];
    else if (c == 6) v = b_embed[j];
    else             v = start_embed[j];
    xin[j] = v;
    __syncthreads();
    const float* Wg = (g == 0) ? W_z : (g == 1) ? W_r : W_h;  // top half rows 0..255
    const float* bg = (g == 0) ? b_z : (g == 1) ? b_r : b_h;
    float acc = bg[j];                       // fold gate bias into pre table
    for (int k = 0; k < HD; ++k) acc += xin[k] * Wg[k * HD + j];
    pre[(g * 8 + c) * HD + j] = acc;
    return;
  }
  if (bid >= 136) {  // W_out frags: single mt, KC=8; A[m][k] = W_out[k][m] (m<6)
    int id2 = (bid - 136) * 256 + threadIdx.x;   // 0..511
    int kc = id2 >> 6, lane = id2 & 63;
    int m = lane & 15, k0 = kc * 32 + ((lane >> 4) & 3) * 8;
    __align__(16) unsigned short P[3][8];
#pragma unroll
    for (int j = 0; j < 8; ++j) {
      float w = (m < VT) ? W_out[(size_t)(k0 + j) * VT + m] : 0.f;
      unsigned short h1 = f2bf(w);  float r1 = w - bf2f(h1);
      unsigned short h2 = f2bf(r1); float r2 = r1 - bf2f(h2);
      P[0][j] = h1; P[1][j] = h2; P[2][j] = f2bf(r2);
    }
    for (int p = 0; p < 3; ++p) {
      unsigned short* d = woutf + ((size_t)(p * 8 + kc) * 512) + (size_t)lane * 8;
      *(uint4*)d = *(const uint4*)P[p];
    }
    return;
  }
  int id = (bid - 24) * 256 + threadIdx.x;   // 0 .. 28671
  const float* src; unsigned short* dst; int kc, mt, lane, KC, krow0;
  if (id < 4096) {            // encoder frags: KC=4 (K=128)
    lane = id & 63; mt = (id >> 6) & 15; kc = id >> 10;
    src = W_enc; dst = encf; KC = 4; krow0 = 0;
  } else {                    // gate frags: KC=8 (K=256), bottom half rows 256..511
    int rem = id - 4096; int g = rem >> 13; int rr = rem & 8191;
    lane = rr & 63; mt = (rr >> 6) & 15; kc = rr >> 10;
    src = (g == 0) ? W_z : (g == 1) ? W_r : W_h;
    dst = (g == 0) ? zf  : (g == 1) ? rf  : hf;
    KC = 8; krow0 = 256;
  }
  const int m  = mt * 16 + (lane & 15);
  const int k0 = kc * 32 + ((lane >> 4) & 3) * 8;
  __align__(16) unsigned short P[3][8];
#pragma unroll
  for (int j = 0; j < 8; ++j) {
    float w = src[(size_t)(krow0 + k0 + j) * HD + m];
    unsigned short h1 = f2bf(w);  float r1 = w - bf2f(h1);
    unsigned short h2 = f2bf(r1); float r2 = r1 - bf2f(h2);
    P[0][j] = h1; P[1][j] = h2; P[2][j] = f2bf(r2);   // hi+mid+lo == w exactly
  }
  for (int p = 0; p < 3; ++p) {
    unsigned short* d = dst + ((size_t)(p * KC + kc) * 16 + mt) * 512 + (size_t)lane * 8;
    *(uint4*)d = *(const uint4*)P[p];
  }
}

// GEMM pass: A = W frags (global/L2), B = h planes (LDS, conflict-free).
// Wave owns mt = wave*4 + mtl. NG=2 shares B across two A streams (z+r fused).
template<int KC, int NG>
__device__ __forceinline__ void gemm_pass(const unsigned short* __restrict__ f0,
                                          const unsigned short* __restrict__ f1,
                                          const unsigned short* hp_s,
                                          int wave, int lane,
                                          f32x4 acc0[4][2], f32x4 acc1[4][2]) {
#pragma unroll 1
  for (int kc = 0; kc < KC; ++kc) {
    bfrag B[3][2];
#pragma unroll
    for (int p = 0; p < 3; ++p)
#pragma unroll
      for (int nt = 0; nt < 2; ++nt)
        B[p][nt] = *(const bfrag*)&hp_s[HPS(p, kc, nt, lane, 0)];
#pragma unroll
    for (int mtl = 0; mtl < 4; ++mtl) {
      const int fo = (kc * 16 + wave * 4 + mtl) * 512 + lane * 8;
      bfrag A0[3], A1[3];
#pragma unroll
      for (int p = 0; p < 3; ++p) A0[p] = *(const bfrag*)(f0 + fo + p * (KC * 8192));
      if (NG == 2) {
#pragma unroll
        for (int p = 0; p < 3; ++p) A1[p] = *(const bfrag*)(f1 + fo + p * (KC * 8192));
      }
#pragma unroll
      for (int nt = 0; nt < 2; ++nt) {
        acc0[mtl][nt] = prod6(A0, B[0][nt], B[1][nt], B[2][nt], acc0[mtl][nt]);
        if (NG == 2)
          acc1[mtl][nt] = prod6(A1, B[0][nt], B[1][nt], B[2][nt], acc1[mtl][nt]);
      }
    }
  }
}

// gumbel batch for step s, tile (16 rows), into double-buffered LDS
__device__ __forceinline__ void gen_gumbel(float* __restrict__ gmb, int s, int b0,
                                           int tile, int lane,
                                           uint32_t ka, uint32_t kb) {
  uint32_t basej = (uint32_t)(b0 + tile * 16) * 6u;
#pragma unroll
  for (int rep = 0; rep < 2; ++rep) {
    int d = rep * 64 + lane;
    if (d < 96) {
      uint32_t o0, o1;
      tf2x32(ka, kb, 0u, basej + (uint32_t)d, o0, o1);
      uint32_t bits = o0 ^ o1;
      float f = __uint_as_float((bits >> 9) | 0x3f800000u) - 1.0f;
      float u = (f > 0.f) ? f : 1.175494350822288e-38f;
      float lg1 = (float)log((double)u);
      float lg2 = (float)log((double)(-lg1));
      gmb[((s & 1) * 32 + tile * 16 + d / 6) * 6 + (d % 6)] = -lg2;
    }
  }
}

// ---- main kernel: persistent rollout; h_old in registers; logits via MFMA;
// gumbels generated by waves 2-3 overlapped with waves 0-1's logits GEMM.
__launch_bounds__(NTH, 2)
__global__ void main_kernel(const float* __restrict__ x,
                            const float* __restrict__ b_enc,
                            const float* __restrict__ b_out,
                            const float* __restrict__ pre,
                            const unsigned short* __restrict__ encf,
                            const unsigned short* __restrict__ zf,
                            const unsigned short* __restrict__ rf,
                            const unsigned short* __restrict__ hf,
                            const unsigned short* __restrict__ woutf,
                            float* __restrict__ out, Keys keys) {
  __shared__ __align__(16) unsigned short hp_s[3 * 8 * 1040];  // 49,920 B
  __shared__ float gmb_s[2 * 32 * 6];                          //  1,536 B
  __shared__ float boutL[16];
  __shared__ unsigned state[BM];
  __shared__ float tlp[BM];
  // total ~51.8 KB -> 2 blocks/CU

  const int tid = threadIdx.x;
  const int wave = tid >> 6, lane = tid & 63;
  const int ln = lane & 15, qk = lane >> 4;
  const int b0 = blockIdx.x * BM;

  if (tid < 16) boutL[tid] = (tid < VT) ? b_out[tid] : 0.f;
  if (tid < BM) { state[tid] = 7u; tlp[tid] = 0.f; }

  // stage x (B-operand planes), kc 0..3
  for (int i = tid; i < BM * DIN; i += NTH) {
    int row = i >> 7, k = i & 127;
    float v = x[(size_t)(b0 + row) * DIN + k];
    unsigned short h1 = f2bf(v);  float r1 = v - bf2f(h1);
    unsigned short h2 = f2bf(r1); float r2 = r1 - bf2f(h2);
    int kc = k >> 5, nt = row >> 4, lp = (row & 15) + 16 * ((k >> 3) & 3), j = k & 7;
    hp_s[HPS(0, kc, nt, lp, j)] = h1;
    hp_s[HPS(1, kc, nt, lp, j)] = h2;
    hp_s[HPS(2, kc, nt, lp, j)] = f2bf(r2);
  }
  // waves 2-3: generate step-0 gumbels while others head to barrier
  if (wave >= 2) gen_gumbel(gmb_s, 0, b0, wave - 2, lane, keys.a[0], keys.b[0]);
  __syncthreads();

  f32x4 acc0[4][2], acc1[4][2], z_s[4][2], hold[4][2];

  // ---- encoder: h0 = x @ W_enc + b_enc ----
#pragma unroll
  for (int mtl = 0; mtl < 4; ++mtl) {
    int mb = (wave * 4 + mtl) * 16 + qk * 4;
    f32x4 be = *(const f32x4*)&b_enc[mb];
#pragma unroll
    for (int nt = 0; nt < 2; ++nt) acc0[mtl][nt] = be;
  }
  gemm_pass<4, 1>(encf, nullptr, hp_s, wave, lane, acc0, acc1);
  __syncthreads();  // all x-plane reads done
#pragma unroll
  for (int mtl = 0; mtl < 4; ++mtl) {
    int mb = (wave * 4 + mtl) * 16 + qk * 4;
    int kc = mb >> 5, hi2 = (mb >> 3) & 3, j0 = mb & 7, lp = ln + 16 * hi2;
#pragma unroll
    for (int nt = 0; nt < 2; ++nt) {
      f32x4 o = acc0[mtl][nt];
      hold[mtl][nt] = o;                 // h_old lives in registers from here on
      bh4 P0, P1, P2;
#pragma unroll
      for (int j = 0; j < 4; ++j) {
        float v = o[j];
        unsigned short h1 = f2bf(v);  float r1 = v - bf2f(h1);
        unsigned short h2 = f2bf(r1); float r2 = r1 - bf2f(h2);
        P0[j] = (short)h1; P1[j] = (short)h2; P2[j] = (short)f2bf(r2);
      }
      *(bh4*)&hp_s[HPS(0, kc, nt, lp, j0)] = P0;
      *(bh4*)&hp_s[HPS(1, kc, nt, lp, j0)] = P1;
      *(bh4*)&hp_s[HPS(2, kc, nt, lp, j0)] = P2;
    }
  }
  __syncthreads();

#pragma unroll 1
  for (int t = 0; t < TS; ++t) {
    // ---- fused z+r (C-init from pre tables incl. bias) ----
#pragma unroll
    for (int mtl = 0; mtl < 4; ++mtl) {
      int mb = (wave * 4 + mtl) * 16 + qk * 4;
#pragma unroll
      for (int nt = 0; nt < 2; ++nt) {
        int code = (int)(state[nt * 16 + ln] & 7u);
        acc0[mtl][nt] = *(const f32x4*)&pre[(0 * 8 + code) * 256 + mb];
        acc1[mtl][nt] = *(const f32x4*)&pre[(1 * 8 + code) * 256 + mb];
      }
    }
    gemm_pass<8, 2>(zf, rf, hp_s, wave, lane, acc0, acc1);
    __syncthreads();  // all h-plane reads done
#pragma unroll
    for (int mtl = 0; mtl < 4; ++mtl) {
      int mb = (wave * 4 + mtl) * 16 + qk * 4;
      int kc = mb >> 5, hi2 = (mb >> 3) & 3, j0 = mb & 7, lp = ln + 16 * hi2;
#pragma unroll
      for (int nt = 0; nt < 2; ++nt) {
        f32x4 ho = hold[mtl][nt];
        f32x4 zv;
        bh4 P0, P1, P2;
#pragma unroll
        for (int j = 0; j < 4; ++j) {
          zv[j] = sigf(acc0[mtl][nt][j]);
          float rhv = sigf(acc1[mtl][nt][j]) * ho[j];
          unsigned short h1 = f2bf(rhv); float r1 = rhv - bf2f(h1);
          unsigned short h2 = f2bf(r1);  float r2 = r1 - bf2f(h2);
          P0[j] = (short)h1; P1[j] = (short)h2; P2[j] = (short)f2bf(r2);
        }
        z_s[mtl][nt] = zv;
        *(bh4*)&hp_s[HPS(0, kc, nt, lp, j0)] = P0;
        *(bh4*)&hp_s[HPS(1, kc, nt, lp, j0)] = P1;
        *(bh4*)&hp_s[HPS(2, kc, nt, lp, j0)] = P2;
      }
    }
    __syncthreads();  // rh planes published

    // ---- candidate gate ----
#pragma unroll
    for (int mtl = 0; mtl < 4; ++mtl) {
      int mb = (wave * 4 + mtl) * 16 + qk * 4;
#pragma unroll
      for (int nt = 0; nt < 2; ++nt) {
        int code = (int)(state[nt * 16 + ln] & 7u);
        acc0[mtl][nt] = *(const f32x4*)&pre[(2 * 8 + code) * 256 + mb];
      }
    }
    gemm_pass<8, 1>(hf, nullptr, hp_s, wave, lane, acc0, acc1);
    __syncthreads();  // all rh-plane reads done
#pragma unroll
    for (int mtl = 0; mtl < 4; ++mtl) {
      int mb = (wave * 4 + mtl) * 16 + qk * 4;
      int kc = mb >> 5, hi2 = (mb >> 3) & 3, j0 = mb & 7, lp = ln + 16 * hi2;
#pragma unroll
      for (int nt = 0; nt < 2; ++nt) {
        f32x4 z = z_s[mtl][nt], ho = hold[mtl][nt], hn;
        bh4 P0, P1, P2;
#pragma unroll
        for (int j = 0; j < 4; ++j) {
          float ht = tanhf(acc0[mtl][nt][j]);
          hn[j] = (1.0f - z[j]) * ho[j] + z[j] * ht;
          unsigned short h1 = f2bf(hn[j]); float r1 = hn[j] - bf2f(h1);
          unsigned short h2 = f2bf(r1);    float r2 = r1 - bf2f(h2);
          P0[j] = (short)h1; P1[j] = (short)h2; P2[j] = (short)f2bf(r2);
        }
        hold[mtl][nt] = hn;              // persists to next step
        *(bh4*)&hp_s[HPS(0, kc, nt, lp, j0)] = P0;
        *(bh4*)&hp_s[HPS(1, kc, nt, lp, j0)] = P1;
        *(bh4*)&hp_s[HPS(2, kc, nt, lp, j0)] = P2;
      }
    }
    __syncthreads();  // h_new planes visible

    // ---- logits GEMM (waves 0-1) || gumbel t+1 (waves 2-3) ----
    if (wave < 2) {
      f32x4 lacc;
#pragma unroll
      for (int j = 0; j < 4; ++j) lacc[j] = boutL[qk * 4 + j];
#pragma unroll 1
      for (int kc = 0; kc < 8; ++kc) {
        bfrag B0 = *(const bfrag*)&hp_s[HPS(0, kc, wave, lane, 0)];
        bfrag B1 = *(const bfrag*)&hp_s[HPS(1, kc, wave, lane, 0)];
        bfrag B2 = *(const bfrag*)&hp_s[HPS(2, kc, wave, lane, 0)];
        bfrag A[3];
#pragma unroll
        for (int p = 0; p < 3; ++p)
          A[p] = *(const bfrag*)(woutf + (p * 8 + kc) * 512 + lane * 8);
        lacc = prod6(A, B0, B1, B2, lacc);
      }
      // D[m=qk*4+j][n=ln]: vocab 0..3 at qk=0, vocab 4..5 at qk=1 regs 0..1
      float l4 = __shfl(lacc[0], ln + 16, 64);
      float l5 = __shfl(lacc[1], ln + 16, 64);
      if (qk == 0) {
        const int m = wave * 16 + ln;
        const int row = b0 + m;
        unsigned st = state[m];
        if (!(st & 8u)) {
          float l[VT] = {lacc[0], lacc[1], lacc[2], lacc[3], l4, l5};
          float best = 0.f; int tok = 0;
#pragma unroll
          for (int v = 0; v < VT; ++v) {
            float val = l[v] + gmb_s[((t & 1) * 32 + m) * 6 + v];
            if (v == 0 || val > best) { best = val; tok = v; }
          }
          float lmax = l[0];
#pragma unroll
          for (int v = 1; v < VT; ++v) lmax = fmaxf(lmax, l[v]);
          float s = 0.f;
#pragma unroll
          for (int v = 0; v < VT; ++v) s += expf(l[v] - lmax);
          float lp = (l[tok] - lmax) - logf(s);
          tlp[m] += lp;
          const bool is_stop = (tok == VT - 1);
          unsigned len = ((st >> 4) & 7u) + (is_stop ? 0u : 1u);
#pragma unroll
          for (int v = 0; v < VT; ++v)
            out[(size_t)row * (TS * VT) + t * VT + v] = (v == tok) ? 1.0f : 0.0f;
          state[m] = (unsigned)tok | (is_stop ? 8u : 0u) | (len << 4);
        } else {
#pragma unroll
          for (int v = 0; v < VT; ++v)
            out[(size_t)row * (TS * VT) + t * VT + v] = 0.0f;
          state[m] = 6u | 8u | (st & 0x70u);
        }
      }
    } else if (t + 1 < TS) {
      gen_gumbel(gmb_s, t + 1, b0, wave - 2, lane, keys.a[t + 1], keys.b[t + 1]);
    }
    __syncthreads();  // state/tlp/gumbels visible for next step
  }

  if (tid < BM) {
    const int row = b0 + tid;
    out[(size_t)NB * (TS * VT) + row]      = tlp[tid];
    out[(size_t)NB * (TS * VT) + NB + row] = (float)((state[tid] >> 4) & 7u);
  }
}

extern "C" void kernel_launch(void* const* d_in, const int* in_sizes, int n_in,
                              void* d_out, int out_size, void* d_ws, size_t ws_size,
                              hipStream_t stream) {
  (void)in_sizes; (void)n_in; (void)out_size; (void)ws_size;
  const float* x          = (const float*)d_in[0];
  const float* W_enc      = (const float*)d_in[1];
  const float* b_enc      = (const float*)d_in[2];
  const float* W_embed    = (const float*)d_in[3];
  const float* b_embed    = (const float*)d_in[4];
  const float* W_z        = (const float*)d_in[5];
  const float* b_z        = (const float*)d_in[6];
  const float* W_r        = (const float*)d_in[7];
  const float* b_r        = (const float*)d_in[8];
  const float* W_h        = (const float*)d_in[9];
  const float* b_h        = (const float*)d_in[10];
  const float* W_out      = (const float*)d_in[11];
  const float* b_out      = (const float*)d_in[12];
  const float* start_embed= (const float*)d_in[13];
  float* out = (float*)d_out;

  // workspace: pre [0,24576); enc frags [24576,221184); z [221184,614400);
  // r [614400,1007616); h [1007616,1400832); wout frags [1400832,1425408)
  float* pre = (float*)d_ws;
  unsigned short* encf = (unsigned short*)((char*)d_ws + 24576);
  unsigned short* zfb  = (unsigned short*)((char*)d_ws + 221184);
  unsigned short* rfb  = (unsigned short*)((char*)d_ws + 614400);
  unsigned short* hfb  = (unsigned short*)((char*)d_ws + 1007616);
  unsigned short* wof  = (unsigned short*)((char*)d_ws + 1400832);

  pre_kernel<<<138, 256, 0, stream>>>(W_enc, W_embed, b_embed, start_embed,
                                      W_z, b_z, W_r, b_r, W_h, b_h, W_out,
                                      pre, encf, zfb, rfb, hfb, wof);

  // keys = jax.random.split(jax.random.key(42), 6), partitionable mode
  Keys K;
  for (int t = 0; t < 6; ++t) {
    uint32_t o0, o1;
    tf2x32(0u, 42u, 0u, (uint32_t)t, o0, o1);
    K.a[t] = o0; K.b[t] = o1;
  }

  main_kernel<<<NB / BM, NTH, 0, stream>>>(x, b_enc, b_out,
                                           pre, encf, zfb, rfb, hfb, wof, out, K);
}